// Round 12
// baseline (246.741 us; speedup 1.0000x reference)
//
#include <hip/hip_runtime.h>

#define NN 50000
#define NE 800000
#define NBUCK 196        // coarse buckets: dst>>8
#define BCAP 5120
#define NPART 256
#define EPP (NE / NPART) // 3125

typedef short short8 __attribute__((ext_vector_type(8)));
typedef float f32x4 __attribute__((ext_vector_type(4)));
union U4 { uint4 u; short8 h; };

__device__ __forceinline__ unsigned f2bf(float f) {
  union { float f; unsigned u; } v; v.f = f;
  return (v.u + 0x7FFFu + ((v.u >> 16) & 1u)) >> 16;
}
__device__ __forceinline__ float2 upk(unsigned u) {
  union { unsigned u; float f; } a, b;
  a.u = u << 16; b.u = u & 0xFFFF0000u;
  return make_float2(a.f, b.f);
}
__device__ __forceinline__ float bf2f(unsigned short b) {
  union { unsigned u; float f; } v; v.u = ((unsigned)b) << 16;
  return v.f;
}
__device__ __forceinline__ unsigned pk2(float a, float b) {
  return f2bf(a) | (f2bf(b) << 16);
}

// ---------------- prep: W1T/W2T bf16 transposed+swizzled; zeros gcur ----------------
__global__ __launch_bounds__(256) void k_prep(const float* __restrict__ W1,
                                              const float* __restrict__ W2,
                                              unsigned short* __restrict__ W1T,
                                              unsigned short* __restrict__ W2T,
                                              unsigned* __restrict__ gcur) {
  int b = blockIdx.x, t = threadIdx.x;
  if (b == 0 && t < NBUCK) gcur[t] = 0;
  {
    int idx = b * 256 + t;
    int k = idx >> 7, n = idx & 127;
    W1T[(n << 7) + (k ^ ((n & 7) << 3))] = (unsigned short)f2bf(W1[idx]);
  }
  if (t < 128) {
    int idx = b * 128 + t;
    int k = idx >> 6, n = idx & 63;
    W2T[(n << 7) + (k ^ ((n & 7) << 3))] = (unsigned short)f2bf(W2[idx]);
  }
}

// ---------------- Phase A partition (blocks 0..255) + MFMA GEMM-1 (blocks 256..) ----------------
__global__ __launch_bounds__(256) void k_partmm1(const int* __restrict__ src,
                                                 const int* __restrict__ dst,
                                                 unsigned* __restrict__ gcur,
                                                 unsigned* __restrict__ part,
                                                 const float* __restrict__ X,
                                                 const unsigned short* __restrict__ W1T,
                                                 unsigned* __restrict__ Hbu) {
  __shared__ __attribute__((aligned(16))) unsigned smem[12288];  // 48 KB
  __shared__ int wsum[4];
  const int tid = threadIdx.x;
  if (blockIdx.x < NPART) {
    unsigned* stage = smem;
    unsigned* hist  = smem + 3200;
    unsigned* curs  = smem + 3400;
    unsigned* bbs   = smem + 3600;
    const int e0 = blockIdx.x * EPP;
    for (int i = tid; i < NBUCK; i += 256) hist[i] = 0;
    __syncthreads();
    for (int k = tid; k < EPP; k += 256)
      atomicAdd(&hist[((unsigned)dst[e0 + k]) >> 8], 1u);
    __syncthreads();
    {
      int lane = tid & 63, w = tid >> 6;
      unsigned v = (tid < NBUCK) ? hist[tid] : 0;
      unsigned incl = v;
#pragma unroll
      for (int d = 1; d < 64; d <<= 1) {
        unsigned u = __shfl_up(incl, d);
        if (lane >= d) incl += u;
      }
      if (lane == 63) wsum[w] = (int)incl;
      __syncthreads();
      unsigned wpre = 0;
      for (int j = 0; j < w; ++j) wpre += (unsigned)wsum[j];
      if (tid < NBUCK) curs[tid] = wpre + incl - v;
    }
    __syncthreads();
    for (int k = tid; k < EPP; k += 256) {
      int d = dst[e0 + k];
      unsigned slot = atomicAdd(&curs[((unsigned)d) >> 8], 1u);
      stage[slot] = (((unsigned)src[e0 + k]) << 16) | (unsigned)d;
    }
    __syncthreads();
    if (tid < NBUCK) bbs[tid] = atomicAdd(&gcur[tid], hist[tid]);
    __syncthreads();
    for (int k = tid; k < EPP; k += 256) {
      unsigned v = stage[k];
      unsigned b = (v & 0xFFFFu) >> 8;
      unsigned startb = curs[b] - hist[b];
      part[b * BCAP + bbs[b] + ((unsigned)k - startb)] = v;
    }
  } else {
    uint4* w1t4 = (uint4*)smem;
    uint4* xs4  = (uint4*)(smem + 8192);
    const int base = (blockIdx.x - NPART) * 64;
    const uint4* W1Tg = (const uint4*)W1T;
    const float4* X4 = (const float4*)X;
#pragma unroll
    for (int it = 0; it < 8; ++it) w1t4[tid + 256 * it] = W1Tg[tid + 256 * it];
#pragma unroll
    for (int it = 0; it < 4; ++it) {
      int j = tid + 256 * it;
      int row = j >> 4, c16 = j & 15;
      int grow = base + row;
      uint4 v = make_uint4(0, 0, 0, 0);
      if (grow < NN) {
        float4 f0 = X4[(size_t)grow * 32 + c16 * 2];
        float4 f1 = X4[(size_t)grow * 32 + c16 * 2 + 1];
        v = make_uint4(pk2(f0.x, f0.y), pk2(f0.z, f0.w), pk2(f1.x, f1.y), pk2(f1.z, f1.w));
      }
      xs4[row * 16 + (c16 ^ (row & 7))] = v;
    }
    __syncthreads();
    const int lane = tid & 63, wv = tid >> 6;
    const int l7 = lane & 7, lg = lane >> 4;
    f32x4 acc[8];
#pragma unroll
    for (int c = 0; c < 8; ++c) acc[c] = (f32x4){0.f, 0.f, 0.f, 0.f};
    const int arow = wv * 16 + (lane & 15);
#pragma unroll
    for (int kk = 0; kk < 4; ++kk) {
      int kcc = kk * 4 + lg;
      U4 a; a.u = xs4[arow * 16 + (kcc ^ l7)];
#pragma unroll
      for (int c = 0; c < 8; ++c) {
        int n = c * 16 + (lane & 15);
        U4 b; b.u = w1t4[n * 16 + (kcc ^ l7)];
        acc[c] = __builtin_amdgcn_mfma_f32_16x16x32_bf16(a.h, b.h, acc[c], 0, 0, 0);
      }
    }
#pragma unroll
    for (int c = 0; c < 8; ++c) {
#pragma unroll
      for (int r = 0; r < 4; ++r) {
        int grow = base + wv * 16 + lg * 4 + r;
        unsigned mb = f2bf(acc[c][r]);
        unsigned ob = (unsigned)__shfl_xor((int)mb, 1);
        if (((lane & 1) == 0) && grow < NN)
          Hbu[(size_t)grow * 64 + c * 8 + ((lane & 15) >> 1)] = mb | (ob << 16);
      }
    }
  }
}

// ---------------- Phase B: per-bucket (slab,dst) sort -> sedge u32, off2 int2, dinv ----------------
// key = (slab<<8)|dstbin, slab = src>>13 (8192-row slabs, 2MB bf16 -> L2-resident)
__global__ __launch_bounds__(256) void k_bucket(const unsigned* __restrict__ gcur,
                                                const unsigned* __restrict__ part,
                                                float* __restrict__ dinv,
                                                unsigned* __restrict__ sedge,
                                                int2* __restrict__ off2) {
  __shared__ unsigned hist[2048], curs[2048], sb[256];
  __shared__ unsigned ssr[BCAP];  // 20 KB
  __shared__ int wsum[4];
  const int tid = threadIdx.x, b = blockIdx.x;
  const int lane = tid & 63, w = tid >> 6;
  {  // bucket-base exclusive scan of gcur
    unsigned g = (tid < NBUCK) ? gcur[tid] : 0;
    unsigned incl = g;
#pragma unroll
    for (int d = 1; d < 64; d <<= 1) {
      unsigned u = __shfl_up(incl, d);
      if (lane >= d) incl += u;
    }
    if (lane == 63) wsum[w] = (int)incl;
    __syncthreads();
    unsigned wpre = 0;
    for (int j = 0; j < w; ++j) wpre += (unsigned)wsum[j];
    sb[tid] = wpre + incl - g;
  }
  __syncthreads();
  const int nb = (int)gcur[b];
  const int base = (int)sb[b];
  const unsigned* pp = part + (size_t)b * BCAP;
  for (int i = tid; i < 2048; i += 256) hist[i] = 0;
  __syncthreads();
  for (int k = tid; k < nb; k += 256) {
    unsigned vv = pp[k];
    unsigned key = (((vv >> 16) >> 13) << 8) | (vv & 255u);
    atomicAdd(&hist[key], 1u);
  }
  __syncthreads();
  // scan 2048 bins (bin-index order): thread t owns bins 8t..8t+7
  unsigned hloc[8];
  unsigned tsum = 0;
#pragma unroll
  for (int i = 0; i < 8; ++i) { hloc[i] = hist[tid * 8 + i]; tsum += hloc[i]; }
  unsigned incl = tsum;
#pragma unroll
  for (int d = 1; d < 64; d <<= 1) {
    unsigned u = __shfl_up(incl, d);
    if (lane >= d) incl += u;
  }
  if (lane == 63) wsum[w] = (int)incl;
  __syncthreads();
  unsigned wpre = 0;
  for (int j = 0; j < w; ++j) wpre += (unsigned)wsum[j];
  unsigned run = wpre + incl - tsum;
#pragma unroll
  for (int i = 0; i < 8; ++i) { curs[tid * 8 + i] = run; run += hloc[i]; }
  __syncthreads();
  // per-node: dinv + off2 segments (node dstbin = tid, slabs s: bin = (s<<8)|tid)
  {
    int node = b * 256 + tid;
    if (node < NN) {
      unsigned cnt = 0;
#pragma unroll
      for (int s = 0; s < 8; ++s) cnt += hist[(s << 8) | tid];
      dinv[node] = rsqrtf((float)(cnt + 1));
#pragma unroll
      for (int s = 0; s < 8; ++s) {
        unsigned bin = (s << 8) | tid;
        int st = base + (int)curs[bin];
        int en = (bin == 2047) ? (base + nb) : (base + (int)curs[bin + 1]);
        off2[(size_t)node * 8 + s] = make_int2(st, en);
      }
    }
  }
  __syncthreads();
  for (int k = tid; k < nb; k += 256) {
    unsigned vv = pp[k];
    unsigned key = (((vv >> 16) >> 13) << 8) | (vv & 255u);
    unsigned slot = atomicAdd(&curs[key], 1u);
    ssr[slot] = vv;
  }
  __syncthreads();
  for (int k = tid; k < nb; k += 256) sedge[base + k] = ssr[k];
}

// ---------------- agg1 v2: 64-node block, fp32 LDS acc, slab-synchronized ----------------
__global__ __launch_bounds__(256) void k_agg1(const unsigned* __restrict__ Hb,
                                              const int2* __restrict__ off2,
                                              const unsigned* __restrict__ sedge,
                                              const float* __restrict__ dinv,
                                              const float* __restrict__ b1,
                                              unsigned* __restrict__ H2) {
  __shared__ __attribute__((aligned(16))) float accL[64][128];  // 32 KB
  const int tid = threadIdx.x, lane = tid & 63, w = tid >> 6;
  const int q = blockIdx.x & 3;
  const int n0 = (blockIdx.x >> 2) * 256 + q * 64 + w * 16;
  const int qbase = (blockIdx.x >> 2) * 256 + q * 64;
  // init rows from self term: acc = dn * h[n]
#pragma unroll
  for (int i = 0; i < 16; ++i) {
    int n = n0 + i;
    float2 v = make_float2(0.f, 0.f);
    if (n < NN) {
      float dn = dinv[n];
      float2 f = upk(Hb[(size_t)n * 64 + lane]);
      v = make_float2(dn * f.x, dn * f.y);
    }
    *(float2*)&accL[w * 16 + i][2 * lane] = v;
  }
  int last = n0 + 15;
  if (last >= NN) last = NN - 1;
  for (int s = 0; s < 8; ++s) {
    __syncthreads();  // slab synchrony across the block
    if (n0 < NN) {
      int js = off2[(size_t)n0 * 8 + s].x;
      int je = off2[(size_t)last * 8 + s].y;
      int j = js;
      for (; j + 1 < je; j += 2) {
        unsigned e0 = sedge[j], e1 = sedge[j + 1];
        unsigned s0 = e0 >> 16, s1 = e1 >> 16;
        int r0 = (int)(e0 & 255u) - q * 64;
        int r1 = (int)(e1 & 255u) - q * 64;
        float w0 = dinv[s0], w1 = dinv[s1];
        unsigned u0 = Hb[(size_t)s0 * 64 + lane];
        unsigned u1 = Hb[(size_t)s1 * 64 + lane];
        float2 f0 = upk(u0), f1 = upk(u1);
        float2 a0 = *(float2*)&accL[r0][2 * lane];
        a0.x = fmaf(f0.x, w0, a0.x); a0.y = fmaf(f0.y, w0, a0.y);
        *(float2*)&accL[r0][2 * lane] = a0;
        float2 a1 = *(float2*)&accL[r1][2 * lane];
        a1.x = fmaf(f1.x, w1, a1.x); a1.y = fmaf(f1.y, w1, a1.y);
        *(float2*)&accL[r1][2 * lane] = a1;
      }
      if (j < je) {
        unsigned e0 = sedge[j];
        unsigned s0 = e0 >> 16;
        int r0 = (int)(e0 & 255u) - q * 64;
        float w0 = dinv[s0];
        float2 f0 = upk(Hb[(size_t)s0 * 64 + lane]);
        float2 a0 = *(float2*)&accL[r0][2 * lane];
        a0.x = fmaf(f0.x, w0, a0.x); a0.y = fmaf(f0.y, w0, a0.y);
        *(float2*)&accL[r0][2 * lane] = a0;
      }
    }
  }
  __syncthreads();
  float2 bb = ((const float2*)b1)[lane];
#pragma unroll
  for (int i = 0; i < 16; ++i) {
    int n = n0 + i;
    if (n < NN) {
      float dn = dinv[n];
      float2 a = *(float2*)&accL[w * 16 + i][2 * lane];
      H2[(size_t)n * 64 + lane] = pk2(fmaxf(fmaf(dn, a.x, bb.x), 0.f),
                                      fmaxf(fmaf(dn, a.y, bb.y), 0.f));
    }
  }
  (void)qbase;
}

// ---------------- MFMA GEMM-2 (unchanged) ----------------
__global__ __launch_bounds__(256) void k_mm2(const unsigned* __restrict__ H2,
                                             const unsigned short* __restrict__ W2T,
                                             const float* __restrict__ dinv,
                                             unsigned* __restrict__ H3u) {
  __shared__ __attribute__((aligned(16))) unsigned smem[8192];
  uint4* w2t4 = (uint4*)smem;
  uint4* xs4  = (uint4*)(smem + 4096);
  const int tid = threadIdx.x;
  const int base = blockIdx.x * 64;
  const uint4* W2Tg = (const uint4*)W2T;
  const uint4* H2v = (const uint4*)H2;
#pragma unroll
  for (int it = 0; it < 4; ++it) w2t4[tid + 256 * it] = W2Tg[tid + 256 * it];
#pragma unroll
  for (int it = 0; it < 4; ++it) {
    int j = tid + 256 * it;
    int row = j >> 4, c16 = j & 15;
    int grow = base + row;
    uint4 v = (grow < NN) ? H2v[(size_t)grow * 16 + c16] : make_uint4(0, 0, 0, 0);
    xs4[row * 16 + (c16 ^ (row & 7))] = v;
  }
  __syncthreads();
  const int lane = tid & 63, wv = tid >> 6;
  const int l7 = lane & 7, lg = lane >> 4;
  f32x4 acc[4];
#pragma unroll
  for (int c = 0; c < 4; ++c) acc[c] = (f32x4){0.f, 0.f, 0.f, 0.f};
  const int arow = wv * 16 + (lane & 15);
#pragma unroll
  for (int kk = 0; kk < 4; ++kk) {
    int kcc = kk * 4 + lg;
    U4 a; a.u = xs4[arow * 16 + (kcc ^ l7)];
#pragma unroll
    for (int c = 0; c < 4; ++c) {
      int n = c * 16 + (lane & 15);
      U4 b; b.u = w2t4[n * 16 + (kcc ^ l7)];
      acc[c] = __builtin_amdgcn_mfma_f32_16x16x32_bf16(a.h, b.h, acc[c], 0, 0, 0);
    }
  }
#pragma unroll
  for (int c = 0; c < 4; ++c) {
#pragma unroll
    for (int r = 0; r < 4; ++r) {
      int grow = base + wv * 16 + lg * 4 + r;
      float dn = (grow < NN) ? dinv[grow] : 0.f;
      unsigned mb = f2bf(acc[c][r] * dn);
      unsigned ob = (unsigned)__shfl_xor((int)mb, 1);
      if (((lane & 1) == 0) && grow < NN)
        H3u[(size_t)grow * 32 + c * 8 + ((lane & 15) >> 1)] = mb | (ob << 16);
    }
  }
}

// ---------------- agg2 v2: 64-node block, fp32 LDS acc, slab-synchronized ----------------
__global__ __launch_bounds__(256) void k_agg2(const unsigned short* __restrict__ H3,
                                              const int2* __restrict__ off2,
                                              const unsigned* __restrict__ sedge,
                                              const float* __restrict__ dinv,
                                              const float* __restrict__ b2,
                                              float* __restrict__ out) {
  __shared__ __attribute__((aligned(16))) float accL[64][64];  // 16 KB
  const int tid = threadIdx.x, lane = tid & 63, w = tid >> 6;
  const int q = blockIdx.x & 3;
  const int n0 = (blockIdx.x >> 2) * 256 + q * 64 + w * 16;
#pragma unroll
  for (int i = 0; i < 16; ++i) {
    int n = n0 + i;
    float v = 0.f;
    if (n < NN) v = bf2f(H3[(size_t)n * 64 + lane]);  // H3 prescaled by dinv
    accL[w * 16 + i][lane] = v;
  }
  int last = n0 + 15;
  if (last >= NN) last = NN - 1;
  for (int s = 0; s < 8; ++s) {
    __syncthreads();
    if (n0 < NN) {
      int js = off2[(size_t)n0 * 8 + s].x;
      int je = off2[(size_t)last * 8 + s].y;
      int j = js;
      for (; j + 1 < je; j += 2) {
        unsigned e0 = sedge[j], e1 = sedge[j + 1];
        unsigned s0 = e0 >> 16, s1 = e1 >> 16;
        int r0 = (int)(e0 & 255u) - q * 64;
        int r1 = (int)(e1 & 255u) - q * 64;
        float h0 = bf2f(H3[(size_t)s0 * 64 + lane]);
        float h1 = bf2f(H3[(size_t)s1 * 64 + lane]);
        accL[r0][lane] += h0;
        accL[r1][lane] += h1;
      }
      if (j < je) {
        unsigned e0 = sedge[j];
        unsigned s0 = e0 >> 16;
        int r0 = (int)(e0 & 255u) - q * 64;
        accL[r0][lane] += bf2f(H3[(size_t)s0 * 64 + lane]);
      }
    }
  }
  __syncthreads();
  float bb = b2[lane];
#pragma unroll
  for (int i = 0; i < 16; ++i) {
    int n = n0 + i;
    if (n < NN) {
      float dn = dinv[n];
      out[(size_t)n * 64 + lane] = fmaxf(fmaf(dn, accL[w * 16 + i][lane], bb), 0.f);
    }
  }
}

extern "C" void kernel_launch(void* const* d_in, const int* in_sizes, int n_in,
                              void* d_out, int out_size, void* d_ws, size_t ws_size,
                              hipStream_t stream) {
  const float* x  = (const float*)d_in[0];
  const int*   ei = (const int*)d_in[1];
  const float* W1 = (const float*)d_in[2];
  const float* b1 = (const float*)d_in[3];
  const float* W2 = (const float*)d_in[4];
  const float* b2 = (const float*)d_in[5];
  const int* esrc = ei;
  const int* edst = ei + NE;

  char* ws = (char*)d_ws;
  unsigned* gcur  = (unsigned*)(ws + 0);                 // 784 B
  float*    dinv  = (float*)(ws + 4096);                 // 200 KB
  int2*     off2  = (int2*)(ws + 204800);                // NN*8*8 = 3.2 MB
  unsigned* sedge = (unsigned*)(ws + 3407872);           // 3.2 MB
  unsigned short* W1T = (unsigned short*)(ws + 6608896); // 32 KB
  unsigned short* W2T = (unsigned short*)(ws + 6641664); // 16 KB
  unsigned* part  = (unsigned*)(ws + 8388608);           // ~4 MB
  unsigned* Hb    = (unsigned*)(ws + 12582912);          // 12.8 MB
  unsigned* H2    = (unsigned*)(ws + 25690112);          // 12.8 MB
  unsigned short* H3 = (unsigned short*)(ws + 38535168); // 6.4 MB

  hipLaunchKernelGGL(k_prep, dim3(64), dim3(256), 0, stream, W1, W2, W1T, W2T, gcur);
  hipLaunchKernelGGL(k_partmm1, dim3(NPART + (NN + 63) / 64), dim3(256), 0, stream,
                     esrc, edst, gcur, part, x, W1T, Hb);
  hipLaunchKernelGGL(k_bucket, dim3(NBUCK), dim3(256), 0, stream,
                     gcur, part, dinv, sedge, off2);
  hipLaunchKernelGGL(k_agg1, dim3(NBUCK * 4), dim3(256), 0, stream,
                     Hb, off2, sedge, dinv, b1, H2);
  hipLaunchKernelGGL(k_mm2, dim3((NN + 63) / 64), dim3(256), 0, stream,
                     H2, W2T, dinv, (unsigned*)H3);
  hipLaunchKernelGGL(k_agg2, dim3(NBUCK * 4), dim3(256), 0, stream,
                     H3, off2, sedge, dinv, b2, (float*)d_out);
}

// Round 13
// 171.599 us; speedup vs baseline: 1.4379x; 1.4379x over previous
//
#include <hip/hip_runtime.h>

#define NN 50000
#define NE 800000
#define NBUCK 196        // coarse buckets: dst>>8
#define BCAP 5120
#define NPART 256
#define EPP (NE / NPART) // 3125

typedef short short8 __attribute__((ext_vector_type(8)));
typedef float f32x4 __attribute__((ext_vector_type(4)));
union U4 { uint4 u; short8 h; };

__device__ __forceinline__ unsigned f2bf(float f) {
  union { float f; unsigned u; } v; v.f = f;
  return (v.u + 0x7FFFu + ((v.u >> 16) & 1u)) >> 16;
}
__device__ __forceinline__ float2 upk(unsigned u) {
  union { unsigned u; float f; } a, b;
  a.u = u << 16; b.u = u & 0xFFFF0000u;
  return make_float2(a.f, b.f);
}
__device__ __forceinline__ float bf2f(unsigned short b) {
  union { unsigned u; float f; } v; v.u = ((unsigned)b) << 16;
  return v.f;
}
__device__ __forceinline__ unsigned pk2(float a, float b) {
  return f2bf(a) | (f2bf(b) << 16);
}

// ---------------- early degree histogram (R4-validated shape): no global atomics ----------------
__global__ __launch_bounds__(256) void k_deg_hist(const int* __restrict__ dst,
                                                  unsigned* __restrict__ partial) {
  __shared__ unsigned h[12500];  // 50 KB, u16-pair packed
  const int b = blockIdx.x, tid = threadIdx.x;
  const int e0 = b * 12500;
  unsigned* pb = partial + (size_t)b * 25000;
#pragma unroll
  for (int r = 0; r < 2; ++r) {
    for (int i = tid; i < 12500; i += 256) h[i] = 0;
    __syncthreads();
    const int lo = r * 25000;
    for (int k = tid; k < 12500; k += 256) {
      int ld = dst[e0 + k] - lo;
      if ((unsigned)ld < 25000u)
        atomicAdd(&h[ld >> 1], 1u << (16 * (ld & 1)));
    }
    __syncthreads();
    for (int i = tid; i < 12500; i += 256) pb[r * 12500 + i] = h[i];
    __syncthreads();
  }
}

__global__ __launch_bounds__(256) void k_deg_merge(const unsigned* __restrict__ partial,
                                                   float* __restrict__ dinv) {
  int w = blockIdx.x * 256 + threadIdx.x;
  if (w >= 25000) return;
  unsigned s0 = 0, s1 = 0;
  for (int b = 0; b < 64; ++b) {
    unsigned v = partial[(size_t)b * 25000 + w];
    s0 += v & 0xFFFFu;
    s1 += v >> 16;
  }
  ((float2*)dinv)[w] = make_float2(rsqrtf((float)(s0 + 1)), rsqrtf((float)(s1 + 1)));
}

// ---------------- prep: W1T/W2T bf16 transposed+swizzled; zeros gcur ----------------
__global__ __launch_bounds__(256) void k_prep(const float* __restrict__ W1,
                                              const float* __restrict__ W2,
                                              unsigned short* __restrict__ W1T,
                                              unsigned short* __restrict__ W2T,
                                              unsigned* __restrict__ gcur) {
  int b = blockIdx.x, t = threadIdx.x;
  if (b == 0 && t < NBUCK) gcur[t] = 0;
  {
    int idx = b * 256 + t;
    int k = idx >> 7, n = idx & 127;
    W1T[(n << 7) + (k ^ ((n & 7) << 3))] = (unsigned short)f2bf(W1[idx]);
  }
  if (t < 128) {
    int idx = b * 128 + t;
    int k = idx >> 6, n = idx & 63;
    W2T[(n << 7) + (k ^ ((n & 7) << 3))] = (unsigned short)f2bf(W2[idx]);
  }
}

// ---------------- Phase A partition (blocks 0..255) + MFMA GEMM-1 (blocks 256..) ----------------
// GEMM-1 epilogue prescales by dinv[row]: Hb[n] = bf16(dinv[n] * (X@W1)[n])
__global__ __launch_bounds__(256) void k_partmm1(const int* __restrict__ src,
                                                 const int* __restrict__ dst,
                                                 unsigned* __restrict__ gcur,
                                                 unsigned* __restrict__ part,
                                                 const float* __restrict__ X,
                                                 const unsigned short* __restrict__ W1T,
                                                 const float* __restrict__ dinv,
                                                 unsigned* __restrict__ Hbu) {
  __shared__ __attribute__((aligned(16))) unsigned smem[12288];  // 48 KB
  __shared__ int wsum[4];
  const int tid = threadIdx.x;
  if (blockIdx.x < NPART) {
    unsigned* stage = smem;
    unsigned* hist  = smem + 3200;
    unsigned* curs  = smem + 3400;
    unsigned* bbs   = smem + 3600;
    const int e0 = blockIdx.x * EPP;
    for (int i = tid; i < NBUCK; i += 256) hist[i] = 0;
    __syncthreads();
    for (int k = tid; k < EPP; k += 256)
      atomicAdd(&hist[((unsigned)dst[e0 + k]) >> 8], 1u);
    __syncthreads();
    {
      int lane = tid & 63, w = tid >> 6;
      unsigned v = (tid < NBUCK) ? hist[tid] : 0;
      unsigned incl = v;
#pragma unroll
      for (int d = 1; d < 64; d <<= 1) {
        unsigned u = __shfl_up(incl, d);
        if (lane >= d) incl += u;
      }
      if (lane == 63) wsum[w] = (int)incl;
      __syncthreads();
      unsigned wpre = 0;
      for (int j = 0; j < w; ++j) wpre += (unsigned)wsum[j];
      if (tid < NBUCK) curs[tid] = wpre + incl - v;
    }
    __syncthreads();
    for (int k = tid; k < EPP; k += 256) {
      int d = dst[e0 + k];
      unsigned slot = atomicAdd(&curs[((unsigned)d) >> 8], 1u);
      stage[slot] = (((unsigned)src[e0 + k]) << 16) | (unsigned)d;
    }
    __syncthreads();
    if (tid < NBUCK) bbs[tid] = atomicAdd(&gcur[tid], hist[tid]);
    __syncthreads();
    for (int k = tid; k < EPP; k += 256) {
      unsigned v = stage[k];
      unsigned b = (v & 0xFFFFu) >> 8;
      unsigned startb = curs[b] - hist[b];
      part[b * BCAP + bbs[b] + ((unsigned)k - startb)] = v;
    }
  } else {
    uint4* w1t4 = (uint4*)smem;
    uint4* xs4  = (uint4*)(smem + 8192);
    const int base = (blockIdx.x - NPART) * 64;
    const uint4* W1Tg = (const uint4*)W1T;
    const float4* X4 = (const float4*)X;
#pragma unroll
    for (int it = 0; it < 8; ++it) w1t4[tid + 256 * it] = W1Tg[tid + 256 * it];
#pragma unroll
    for (int it = 0; it < 4; ++it) {
      int j = tid + 256 * it;
      int row = j >> 4, c16 = j & 15;
      int grow = base + row;
      uint4 v = make_uint4(0, 0, 0, 0);
      if (grow < NN) {
        float4 f0 = X4[(size_t)grow * 32 + c16 * 2];
        float4 f1 = X4[(size_t)grow * 32 + c16 * 2 + 1];
        v = make_uint4(pk2(f0.x, f0.y), pk2(f0.z, f0.w), pk2(f1.x, f1.y), pk2(f1.z, f1.w));
      }
      xs4[row * 16 + (c16 ^ (row & 7))] = v;
    }
    __syncthreads();
    const int lane = tid & 63, wv = tid >> 6;
    const int l7 = lane & 7, lg = lane >> 4;
    f32x4 acc[8];
#pragma unroll
    for (int c = 0; c < 8; ++c) acc[c] = (f32x4){0.f, 0.f, 0.f, 0.f};
    const int arow = wv * 16 + (lane & 15);
#pragma unroll
    for (int kk = 0; kk < 4; ++kk) {
      int kcc = kk * 4 + lg;
      U4 a; a.u = xs4[arow * 16 + (kcc ^ l7)];
#pragma unroll
      for (int c = 0; c < 8; ++c) {
        int n = c * 16 + (lane & 15);
        U4 b; b.u = w1t4[n * 16 + (kcc ^ l7)];
        acc[c] = __builtin_amdgcn_mfma_f32_16x16x32_bf16(a.h, b.h, acc[c], 0, 0, 0);
      }
    }
#pragma unroll
    for (int c = 0; c < 8; ++c) {
#pragma unroll
      for (int r = 0; r < 4; ++r) {
        int grow = base + wv * 16 + lg * 4 + r;
        float dn = (grow < NN) ? dinv[grow] : 0.f;
        unsigned mb = f2bf(acc[c][r] * dn);
        unsigned ob = (unsigned)__shfl_xor((int)mb, 1);
        if (((lane & 1) == 0) && grow < NN)
          Hbu[(size_t)grow * 64 + c * 8 + ((lane & 15) >> 1)] = mb | (ob << 16);
      }
    }
  }
}

// ---------------- Phase B: per-bucket bin sort (fused base-scan) -> off, ssrc u16 ----------------
__global__ __launch_bounds__(256) void k_bucket(const unsigned* __restrict__ gcur,
                                                const unsigned* __restrict__ part,
                                                int* __restrict__ off,
                                                unsigned short* __restrict__ ssrc) {
  __shared__ unsigned hist[256], curs[256], sb[256];
  __shared__ unsigned short ssr[BCAP];
  __shared__ int wsum[4];
  const int tid = threadIdx.x, b = blockIdx.x;
  const int lane = tid & 63, w = tid >> 6;
  {  // fused exclusive scan of gcur
    unsigned g = (tid < NBUCK) ? gcur[tid] : 0;
    unsigned incl = g;
#pragma unroll
    for (int d = 1; d < 64; d <<= 1) {
      unsigned u = __shfl_up(incl, d);
      if (lane >= d) incl += u;
    }
    if (lane == 63) wsum[w] = (int)incl;
    __syncthreads();
    unsigned wpre = 0;
    for (int j = 0; j < w; ++j) wpre += (unsigned)wsum[j];
    sb[tid] = wpre + incl - g;
  }
  __syncthreads();
  const int nb = (int)gcur[b];
  const int base = (int)sb[b];
  const unsigned* pp = part + (size_t)b * BCAP;
  hist[tid] = 0;
  __syncthreads();
  for (int k = tid; k < nb; k += 256) atomicAdd(&hist[pp[k] & 255u], 1u);
  __syncthreads();
  unsigned v = hist[tid];
  unsigned incl = v;
#pragma unroll
  for (int d = 1; d < 64; d <<= 1) {
    unsigned u = __shfl_up(incl, d);
    if (lane >= d) incl += u;
  }
  if (lane == 63) wsum[w] = (int)incl;
  __syncthreads();
  unsigned wpre = 0;
  for (int j = 0; j < w; ++j) wpre += (unsigned)wsum[j];
  unsigned excl = wpre + incl - v;
  curs[tid] = excl;
  int node = b * 256 + tid;
  if (node < NN) {
    off[node] = base + (int)excl;
  } else if (node == NN) {
    off[NN] = base + (int)excl;
  }
  __syncthreads();
  for (int k = tid; k < nb; k += 256) {
    unsigned vv = pp[k];
    unsigned slot = atomicAdd(&curs[vv & 255u], 1u);
    ssr[slot] = (unsigned short)(vv >> 16);
  }
  __syncthreads();
  for (int k = tid; k < nb; k += 256) ssrc[base + k] = ssr[k];
}

// ---------------- agg1: 4 feature-passes of 64B slices (L2-resident working set) ----------------
// wave = 4 node-groups x 16 lanes; Hb prescaled by dinv; pure-add accumulate.
__global__ __launch_bounds__(256) void k_agg1(const unsigned* __restrict__ Hb,
                                              const int* __restrict__ off,
                                              const unsigned short* __restrict__ ssrc,
                                              const float* __restrict__ dinv,
                                              const float* __restrict__ b1,
                                              unsigned* __restrict__ H2) {
  const int tid = threadIdx.x;
  const int lane = tid & 63, w = tid >> 6;
  const int g = lane >> 4;   // node-group within wave
  const int f = lane & 15;   // u32 column within slice
#pragma unroll
  for (int p = 0; p < 4; ++p) {     // feature pass: cols [16p,16p+16) -> 3.2 MB slice
    const int col = p * 16 + f;
    for (int tile = blockIdx.x; tile < NN / 16; tile += gridDim.x) {
      const int n = tile * 16 + w * 4 + g;
      int jb = off[n], je = off[n + 1];
      float2 acc = upk(Hb[(size_t)n * 64 + col]);  // self term (prescaled)
      int j = jb;
      for (; j + 3 < je; j += 4) {
        unsigned s0 = ssrc[j], s1 = ssrc[j + 1], s2 = ssrc[j + 2], s3 = ssrc[j + 3];
        unsigned u0 = Hb[(size_t)s0 * 64 + col];
        unsigned u1 = Hb[(size_t)s1 * 64 + col];
        unsigned u2 = Hb[(size_t)s2 * 64 + col];
        unsigned u3 = Hb[(size_t)s3 * 64 + col];
        float2 f0 = upk(u0), f1 = upk(u1), f2 = upk(u2), f3 = upk(u3);
        acc.x += f0.x + f1.x + f2.x + f3.x;
        acc.y += f0.y + f1.y + f2.y + f3.y;
      }
      for (; j < je; ++j) {
        float2 f0 = upk(Hb[(size_t)ssrc[j] * 64 + col]);
        acc.x += f0.x;
        acc.y += f0.y;
      }
      float dn = dinv[n];
      float2 bb = ((const float2*)b1)[col];
      H2[(size_t)n * 64 + col] = pk2(fmaxf(fmaf(dn, acc.x, bb.x), 0.f),
                                     fmaxf(fmaf(dn, acc.y, bb.y), 0.f));
    }
  }
}

// ---------------- MFMA GEMM-2: 64 rows x 64 cols per block ----------------
__global__ __launch_bounds__(256) void k_mm2(const unsigned* __restrict__ H2,
                                             const unsigned short* __restrict__ W2T,
                                             const float* __restrict__ dinv,
                                             unsigned* __restrict__ H3u) {
  __shared__ __attribute__((aligned(16))) unsigned smem[8192];
  uint4* w2t4 = (uint4*)smem;
  uint4* xs4  = (uint4*)(smem + 4096);
  const int tid = threadIdx.x;
  const int base = blockIdx.x * 64;
  const uint4* W2Tg = (const uint4*)W2T;
  const uint4* H2v = (const uint4*)H2;
#pragma unroll
  for (int it = 0; it < 4; ++it) w2t4[tid + 256 * it] = W2Tg[tid + 256 * it];
#pragma unroll
  for (int it = 0; it < 4; ++it) {
    int j = tid + 256 * it;
    int row = j >> 4, c16 = j & 15;
    int grow = base + row;
    uint4 v = (grow < NN) ? H2v[(size_t)grow * 16 + c16] : make_uint4(0, 0, 0, 0);
    xs4[row * 16 + (c16 ^ (row & 7))] = v;
  }
  __syncthreads();
  const int lane = tid & 63, wv = tid >> 6;
  const int l7 = lane & 7, lg = lane >> 4;
  f32x4 acc[4];
#pragma unroll
  for (int c = 0; c < 4; ++c) acc[c] = (f32x4){0.f, 0.f, 0.f, 0.f};
  const int arow = wv * 16 + (lane & 15);
#pragma unroll
  for (int kk = 0; kk < 4; ++kk) {
    int kcc = kk * 4 + lg;
    U4 a; a.u = xs4[arow * 16 + (kcc ^ l7)];
#pragma unroll
    for (int c = 0; c < 4; ++c) {
      int n = c * 16 + (lane & 15);
      U4 b; b.u = w2t4[n * 16 + (kcc ^ l7)];
      acc[c] = __builtin_amdgcn_mfma_f32_16x16x32_bf16(a.h, b.h, acc[c], 0, 0, 0);
    }
  }
#pragma unroll
  for (int c = 0; c < 4; ++c) {
#pragma unroll
    for (int r = 0; r < 4; ++r) {
      int grow = base + wv * 16 + lg * 4 + r;
      float dn = (grow < NN) ? dinv[grow] : 0.f;
      unsigned mb = f2bf(acc[c][r] * dn);
      unsigned ob = (unsigned)__shfl_xor((int)mb, 1);
      if (((lane & 1) == 0) && grow < NN)
        H3u[(size_t)grow * 32 + c * 8 + ((lane & 15) >> 1)] = mb | (ob << 16);
    }
  }
}

// ---------------- agg2: R10 shape (scalar loads, 8-deep) ----------------
__global__ __launch_bounds__(256) void k_agg2(const unsigned short* __restrict__ H3,
                                              const int* __restrict__ off,
                                              const unsigned short* __restrict__ ssrc,
                                              const float* __restrict__ dinv,
                                              const float* __restrict__ b2,
                                              float* __restrict__ out) {
  int n = (blockIdx.x * 256 + threadIdx.x) >> 6;
  int lane = threadIdx.x & 63;
  if (n >= NN) return;
  float dn = dinv[n];
  int jb = off[n], je = off[n + 1];
  float acc = bf2f(H3[(size_t)n * 64 + lane]);
  int j = jb;
  for (; j + 7 < je; j += 8) {
    int s0 = ssrc[j], s1 = ssrc[j + 1], s2 = ssrc[j + 2], s3 = ssrc[j + 3];
    int s4 = ssrc[j + 4], s5 = ssrc[j + 5], s6 = ssrc[j + 6], s7 = ssrc[j + 7];
    float h0 = bf2f(H3[(size_t)s0 * 64 + lane]);
    float h1 = bf2f(H3[(size_t)s1 * 64 + lane]);
    float h2 = bf2f(H3[(size_t)s2 * 64 + lane]);
    float h3 = bf2f(H3[(size_t)s3 * 64 + lane]);
    float h4 = bf2f(H3[(size_t)s4 * 64 + lane]);
    float h5 = bf2f(H3[(size_t)s5 * 64 + lane]);
    float h6 = bf2f(H3[(size_t)s6 * 64 + lane]);
    float h7 = bf2f(H3[(size_t)s7 * 64 + lane]);
    acc += h0 + h1 + h2 + h3 + h4 + h5 + h6 + h7;
  }
  for (; j < je; ++j) acc += bf2f(H3[(size_t)ssrc[j] * 64 + lane]);
  out[(size_t)n * 64 + lane] = fmaxf(fmaf(dn, acc, b2[lane]), 0.f);
}

extern "C" void kernel_launch(void* const* d_in, const int* in_sizes, int n_in,
                              void* d_out, int out_size, void* d_ws, size_t ws_size,
                              hipStream_t stream) {
  const float* x  = (const float*)d_in[0];
  const int*   ei = (const int*)d_in[1];
  const float* W1 = (const float*)d_in[2];
  const float* b1 = (const float*)d_in[3];
  const float* W2 = (const float*)d_in[4];
  const float* b2 = (const float*)d_in[5];
  const int* esrc = ei;
  const int* edst = ei + NE;

  char* ws = (char*)d_ws;
  unsigned* gcur  = (unsigned*)(ws + 0);                 // 784 B
  int*      off   = (int*)(ws + 2048);                   // 200 KB
  float*    dinv  = (float*)(ws + 204800);               // 200 KB
  unsigned short* ssrc = (unsigned short*)(ws + 405504); // 1.6 MB
  unsigned short* W1T  = (unsigned short*)(ws + 2013184);// 32 KB
  unsigned short* W2T  = (unsigned short*)(ws + 2045952);// 16 KB
  unsigned* part  = (unsigned*)(ws + 2097152);           // ~4 MB
  unsigned* Hb    = (unsigned*)(ws + 6291456);           // 12.8 MB
  unsigned* H2    = (unsigned*)(ws + 19922944);          // 12.8 MB
  unsigned* partial = (unsigned*)(ws + 19922944);        // 6.4 MB (dead before H2 written)
  unsigned short* H3 = (unsigned short*)(ws + 33554432); // 6.4 MB

  hipLaunchKernelGGL(k_deg_hist, dim3(64), dim3(256), 0, stream, edst, partial);
  hipLaunchKernelGGL(k_prep, dim3(64), dim3(256), 0, stream, W1, W2, W1T, W2T, gcur);
  hipLaunchKernelGGL(k_deg_merge, dim3(98), dim3(256), 0, stream, partial, dinv);
  hipLaunchKernelGGL(k_partmm1, dim3(NPART + (NN + 63) / 64), dim3(256), 0, stream,
                     esrc, edst, gcur, part, x, W1T, dinv, Hb);
  hipLaunchKernelGGL(k_bucket, dim3(NBUCK), dim3(256), 0, stream,
                     gcur, part, off, ssrc);
  hipLaunchKernelGGL(k_agg1, dim3(2048), dim3(256), 0, stream,
                     Hb, off, ssrc, dinv, b1, H2);
  hipLaunchKernelGGL(k_mm2, dim3((NN + 63) / 64), dim3(256), 0, stream,
                     H2, W2T, dinv, (unsigned*)H3);
  hipLaunchKernelGGL(k_agg2, dim3((NN + 3) / 4), dim3(256), 0, stream,
                     H3, off, ssrc, dinv, b2, (float*)d_out);
}

// Round 14
// 119.085 us; speedup vs baseline: 2.0720x; 1.4410x over previous
//
#include <hip/hip_runtime.h>

#define NN 50000
#define NE 800000
#define NBUCK 196        // coarse buckets: dst>>8
#define BCAP 5120
#define NPART 256
#define EPP (NE / NPART) // 3125

typedef short short8 __attribute__((ext_vector_type(8)));
typedef float f32x4 __attribute__((ext_vector_type(4)));
union U4 { uint4 u; short8 h; };

__device__ __forceinline__ unsigned f2bf(float f) {
  union { float f; unsigned u; } v; v.f = f;
  return (v.u + 0x7FFFu + ((v.u >> 16) & 1u)) >> 16;
}
__device__ __forceinline__ float2 upk(unsigned u) {
  union { unsigned u; float f; } a, b;
  a.u = u << 16; b.u = u & 0xFFFF0000u;
  return make_float2(a.f, b.f);
}
__device__ __forceinline__ float bf2f(unsigned short b) {
  union { unsigned u; float f; } v; v.u = ((unsigned)b) << 16;
  return v.f;
}
__device__ __forceinline__ unsigned pk2(float a, float b) {
  return f2bf(a) | (f2bf(b) << 16);
}

// ---------------- prep: W1T/W2T bf16 transposed+swizzled; zeros gcur ----------------
__global__ __launch_bounds__(256) void k_prep(const float* __restrict__ W1,
                                              const float* __restrict__ W2,
                                              unsigned short* __restrict__ W1T,
                                              unsigned short* __restrict__ W2T,
                                              unsigned* __restrict__ gcur) {
  int b = blockIdx.x, t = threadIdx.x;
  if (b == 0 && t < NBUCK) gcur[t] = 0;
  {
    int idx = b * 256 + t;
    int k = idx >> 7, n = idx & 127;
    W1T[(n << 7) + (k ^ ((n & 7) << 3))] = (unsigned short)f2bf(W1[idx]);
  }
  if (t < 128) {
    int idx = b * 128 + t;
    int k = idx >> 6, n = idx & 63;
    W2T[(n << 7) + (k ^ ((n & 7) << 3))] = (unsigned short)f2bf(W2[idx]);
  }
}

// ---------------- Phase A partition (blocks 0..255) + MFMA GEMM-1 (blocks 256..) ----------------
__global__ __launch_bounds__(256) void k_partmm1(const int* __restrict__ src,
                                                 const int* __restrict__ dst,
                                                 unsigned* __restrict__ gcur,
                                                 unsigned* __restrict__ part,
                                                 const float* __restrict__ X,
                                                 const unsigned short* __restrict__ W1T,
                                                 unsigned* __restrict__ Hbu) {
  __shared__ __attribute__((aligned(16))) unsigned smem[12288];  // 48 KB
  __shared__ int wsum[4];
  const int tid = threadIdx.x;
  if (blockIdx.x < NPART) {
    unsigned* stage = smem;
    unsigned* hist  = smem + 3200;
    unsigned* curs  = smem + 3400;
    unsigned* bbs   = smem + 3600;
    const int e0 = blockIdx.x * EPP;
    for (int i = tid; i < NBUCK; i += 256) hist[i] = 0;
    __syncthreads();
    for (int k = tid; k < EPP; k += 256)
      atomicAdd(&hist[((unsigned)dst[e0 + k]) >> 8], 1u);
    __syncthreads();
    {
      int lane = tid & 63, w = tid >> 6;
      unsigned v = (tid < NBUCK) ? hist[tid] : 0;
      unsigned incl = v;
#pragma unroll
      for (int d = 1; d < 64; d <<= 1) {
        unsigned u = __shfl_up(incl, d);
        if (lane >= d) incl += u;
      }
      if (lane == 63) wsum[w] = (int)incl;
      __syncthreads();
      unsigned wpre = 0;
      for (int j = 0; j < w; ++j) wpre += (unsigned)wsum[j];
      if (tid < NBUCK) curs[tid] = wpre + incl - v;
    }
    __syncthreads();
    for (int k = tid; k < EPP; k += 256) {
      int d = dst[e0 + k];
      unsigned slot = atomicAdd(&curs[((unsigned)d) >> 8], 1u);
      stage[slot] = (((unsigned)src[e0 + k]) << 16) | (unsigned)d;
    }
    __syncthreads();
    if (tid < NBUCK) bbs[tid] = atomicAdd(&gcur[tid], hist[tid]);
    __syncthreads();
    for (int k = tid; k < EPP; k += 256) {
      unsigned v = stage[k];
      unsigned b = (v & 0xFFFFu) >> 8;
      unsigned startb = curs[b] - hist[b];
      part[b * BCAP + bbs[b] + ((unsigned)k - startb)] = v;
    }
  } else {
    uint4* w1t4 = (uint4*)smem;
    uint4* xs4  = (uint4*)(smem + 8192);
    const int base = (blockIdx.x - NPART) * 64;
    const uint4* W1Tg = (const uint4*)W1T;
    const float4* X4 = (const float4*)X;
#pragma unroll
    for (int it = 0; it < 8; ++it) w1t4[tid + 256 * it] = W1Tg[tid + 256 * it];
#pragma unroll
    for (int it = 0; it < 4; ++it) {
      int j = tid + 256 * it;
      int row = j >> 4, c16 = j & 15;
      int grow = base + row;
      uint4 v = make_uint4(0, 0, 0, 0);
      if (grow < NN) {
        float4 f0 = X4[(size_t)grow * 32 + c16 * 2];
        float4 f1 = X4[(size_t)grow * 32 + c16 * 2 + 1];
        v = make_uint4(pk2(f0.x, f0.y), pk2(f0.z, f0.w), pk2(f1.x, f1.y), pk2(f1.z, f1.w));
      }
      xs4[row * 16 + (c16 ^ (row & 7))] = v;
    }
    __syncthreads();
    const int lane = tid & 63, wv = tid >> 6;
    const int l7 = lane & 7, lg = lane >> 4;
    f32x4 acc[8];
#pragma unroll
    for (int c = 0; c < 8; ++c) acc[c] = (f32x4){0.f, 0.f, 0.f, 0.f};
    const int arow = wv * 16 + (lane & 15);
#pragma unroll
    for (int kk = 0; kk < 4; ++kk) {
      int kcc = kk * 4 + lg;
      U4 a; a.u = xs4[arow * 16 + (kcc ^ l7)];
#pragma unroll
      for (int c = 0; c < 8; ++c) {
        int n = c * 16 + (lane & 15);
        U4 b; b.u = w1t4[n * 16 + (kcc ^ l7)];
        acc[c] = __builtin_amdgcn_mfma_f32_16x16x32_bf16(a.h, b.h, acc[c], 0, 0, 0);
      }
    }
#pragma unroll
    for (int c = 0; c < 8; ++c) {
#pragma unroll
      for (int r = 0; r < 4; ++r) {
        int grow = base + wv * 16 + lg * 4 + r;
        unsigned mb = f2bf(acc[c][r]);
        unsigned ob = (unsigned)__shfl_xor((int)mb, 1);
        if (((lane & 1) == 0) && grow < NN)
          Hbu[(size_t)grow * 64 + c * 8 + ((lane & 15) >> 1)] = mb | (ob << 16);
      }
    }
  }
}

// ---------------- Phase B: per-bucket bin sort (fused base-scan) -> off, dinv, ssrc ----------------
__global__ __launch_bounds__(256) void k_bucket(const unsigned* __restrict__ gcur,
                                                const unsigned* __restrict__ part,
                                                int* __restrict__ off,
                                                float* __restrict__ dinv,
                                                unsigned short* __restrict__ ssrc) {
  __shared__ unsigned hist[256], curs[256], sb[256];
  __shared__ unsigned short ssr[BCAP];
  __shared__ int wsum[4];
  const int tid = threadIdx.x, b = blockIdx.x;
  const int lane = tid & 63, w = tid >> 6;
  {  // fused exclusive scan of gcur (was k_bksc)
    unsigned g = (tid < NBUCK) ? gcur[tid] : 0;
    unsigned incl = g;
#pragma unroll
    for (int d = 1; d < 64; d <<= 1) {
      unsigned u = __shfl_up(incl, d);
      if (lane >= d) incl += u;
    }
    if (lane == 63) wsum[w] = (int)incl;
    __syncthreads();
    unsigned wpre = 0;
    for (int j = 0; j < w; ++j) wpre += (unsigned)wsum[j];
    sb[tid] = wpre + incl - g;
  }
  __syncthreads();
  const int nb = (int)gcur[b];
  const int base = (int)sb[b];
  const unsigned* pp = part + (size_t)b * BCAP;
  hist[tid] = 0;
  __syncthreads();
  for (int k = tid; k < nb; k += 256) atomicAdd(&hist[pp[k] & 255u], 1u);
  __syncthreads();
  unsigned v = hist[tid];
  unsigned incl = v;
#pragma unroll
  for (int d = 1; d < 64; d <<= 1) {
    unsigned u = __shfl_up(incl, d);
    if (lane >= d) incl += u;
  }
  if (lane == 63) wsum[w] = (int)incl;
  __syncthreads();
  unsigned wpre = 0;
  for (int j = 0; j < w; ++j) wpre += (unsigned)wsum[j];
  unsigned excl = wpre + incl - v;
  curs[tid] = excl;
  int node = b * 256 + tid;
  if (node < NN) {
    off[node] = base + (int)excl;
    dinv[node] = rsqrtf((float)(v + 1));
  } else if (node == NN) {
    off[NN] = base + (int)excl;
  }
  __syncthreads();
  for (int k = tid; k < nb; k += 256) {
    unsigned vv = pp[k];
    unsigned slot = atomicAdd(&curs[vv & 255u], 1u);
    ssr[slot] = (unsigned short)(vv >> 16);
  }
  __syncthreads();
  for (int k = tid; k < nb; k += 256) ssrc[base + k] = ssr[k];
}

// ---------------- agg1 (R10 shape): scalar ssrc loads, dinv FMA, 8-deep MLP ----------------
__global__ __launch_bounds__(256) void k_agg1(const unsigned* __restrict__ Hb,
                                              const int* __restrict__ off,
                                              const unsigned short* __restrict__ ssrc,
                                              const float* __restrict__ dinv,
                                              const float* __restrict__ b1,
                                              unsigned* __restrict__ H2) {
  int n = (blockIdx.x * 256 + threadIdx.x) >> 6;
  int lane = threadIdx.x & 63;
  if (n >= NN) return;
  float dn = dinv[n];
  int jb = off[n], je = off[n + 1];
  float2 self = upk(Hb[(size_t)n * 64 + lane]);
  float2 acc = make_float2(dn * self.x, dn * self.y);
  int j = jb;
  for (; j + 7 < je; j += 8) {
    int s0 = ssrc[j], s1 = ssrc[j + 1], s2 = ssrc[j + 2], s3 = ssrc[j + 3];
    int s4 = ssrc[j + 4], s5 = ssrc[j + 5], s6 = ssrc[j + 6], s7 = ssrc[j + 7];
    float w0 = dinv[s0], w1 = dinv[s1], w2 = dinv[s2], w3 = dinv[s3];
    float w4 = dinv[s4], w5 = dinv[s5], w6 = dinv[s6], w7 = dinv[s7];
    unsigned u0 = Hb[(size_t)s0 * 64 + lane], u1 = Hb[(size_t)s1 * 64 + lane];
    unsigned u2 = Hb[(size_t)s2 * 64 + lane], u3 = Hb[(size_t)s3 * 64 + lane];
    unsigned u4 = Hb[(size_t)s4 * 64 + lane], u5 = Hb[(size_t)s5 * 64 + lane];
    unsigned u6 = Hb[(size_t)s6 * 64 + lane], u7 = Hb[(size_t)s7 * 64 + lane];
    float2 f0 = upk(u0), f1 = upk(u1), f2 = upk(u2), f3 = upk(u3);
    float2 f4 = upk(u4), f5 = upk(u5), f6 = upk(u6), f7 = upk(u7);
    acc.x = fmaf(f0.x, w0, acc.x); acc.y = fmaf(f0.y, w0, acc.y);
    acc.x = fmaf(f1.x, w1, acc.x); acc.y = fmaf(f1.y, w1, acc.y);
    acc.x = fmaf(f2.x, w2, acc.x); acc.y = fmaf(f2.y, w2, acc.y);
    acc.x = fmaf(f3.x, w3, acc.x); acc.y = fmaf(f3.y, w3, acc.y);
    acc.x = fmaf(f4.x, w4, acc.x); acc.y = fmaf(f4.y, w4, acc.y);
    acc.x = fmaf(f5.x, w5, acc.x); acc.y = fmaf(f5.y, w5, acc.y);
    acc.x = fmaf(f6.x, w6, acc.x); acc.y = fmaf(f6.y, w6, acc.y);
    acc.x = fmaf(f7.x, w7, acc.x); acc.y = fmaf(f7.y, w7, acc.y);
  }
  for (; j < je; ++j) {
    int s0 = ssrc[j];
    float w0 = dinv[s0];
    float2 f = upk(Hb[(size_t)s0 * 64 + lane]);
    acc.x = fmaf(f.x, w0, acc.x);
    acc.y = fmaf(f.y, w0, acc.y);
  }
  float2 b = ((const float2*)b1)[lane];
  float hx = fmaxf(fmaf(dn, acc.x, b.x), 0.f);
  float hy = fmaxf(fmaf(dn, acc.y, b.y), 0.f);
  H2[(size_t)n * 64 + lane] = pk2(hx, hy);
}

// ---------------- MFMA GEMM-2: 64 rows x 64 cols per block ----------------
__global__ __launch_bounds__(256) void k_mm2(const unsigned* __restrict__ H2,
                                             const unsigned short* __restrict__ W2T,
                                             const float* __restrict__ dinv,
                                             unsigned* __restrict__ H3u) {
  __shared__ __attribute__((aligned(16))) unsigned smem[8192];
  uint4* w2t4 = (uint4*)smem;
  uint4* xs4  = (uint4*)(smem + 4096);
  const int tid = threadIdx.x;
  const int base = blockIdx.x * 64;
  const uint4* W2Tg = (const uint4*)W2T;
  const uint4* H2v = (const uint4*)H2;
#pragma unroll
  for (int it = 0; it < 4; ++it) w2t4[tid + 256 * it] = W2Tg[tid + 256 * it];
#pragma unroll
  for (int it = 0; it < 4; ++it) {
    int j = tid + 256 * it;
    int row = j >> 4, c16 = j & 15;
    int grow = base + row;
    uint4 v = (grow < NN) ? H2v[(size_t)grow * 16 + c16] : make_uint4(0, 0, 0, 0);
    xs4[row * 16 + (c16 ^ (row & 7))] = v;
  }
  __syncthreads();
  const int lane = tid & 63, wv = tid >> 6;
  const int l7 = lane & 7, lg = lane >> 4;
  f32x4 acc[4];
#pragma unroll
  for (int c = 0; c < 4; ++c) acc[c] = (f32x4){0.f, 0.f, 0.f, 0.f};
  const int arow = wv * 16 + (lane & 15);
#pragma unroll
  for (int kk = 0; kk < 4; ++kk) {
    int kcc = kk * 4 + lg;
    U4 a; a.u = xs4[arow * 16 + (kcc ^ l7)];
#pragma unroll
    for (int c = 0; c < 4; ++c) {
      int n = c * 16 + (lane & 15);
      U4 b; b.u = w2t4[n * 16 + (kcc ^ l7)];
      acc[c] = __builtin_amdgcn_mfma_f32_16x16x32_bf16(a.h, b.h, acc[c], 0, 0, 0);
    }
  }
#pragma unroll
  for (int c = 0; c < 4; ++c) {
#pragma unroll
    for (int r = 0; r < 4; ++r) {
      int grow = base + wv * 16 + lg * 4 + r;
      float dn = (grow < NN) ? dinv[grow] : 0.f;
      unsigned mb = f2bf(acc[c][r] * dn);
      unsigned ob = (unsigned)__shfl_xor((int)mb, 1);
      if (((lane & 1) == 0) && grow < NN)
        H3u[(size_t)grow * 32 + c * 8 + ((lane & 15) >> 1)] = mb | (ob << 16);
    }
  }
}

// ---------------- agg2 (R10 shape) ----------------
__global__ __launch_bounds__(256) void k_agg2(const unsigned short* __restrict__ H3,
                                              const int* __restrict__ off,
                                              const unsigned short* __restrict__ ssrc,
                                              const float* __restrict__ dinv,
                                              const float* __restrict__ b2,
                                              float* __restrict__ out) {
  int n = (blockIdx.x * 256 + threadIdx.x) >> 6;
  int lane = threadIdx.x & 63;
  if (n >= NN) return;
  float dn = dinv[n];
  int jb = off[n], je = off[n + 1];
  float acc = bf2f(H3[(size_t)n * 64 + lane]);
  int j = jb;
  for (; j + 7 < je; j += 8) {
    int s0 = ssrc[j], s1 = ssrc[j + 1], s2 = ssrc[j + 2], s3 = ssrc[j + 3];
    int s4 = ssrc[j + 4], s5 = ssrc[j + 5], s6 = ssrc[j + 6], s7 = ssrc[j + 7];
    float h0 = bf2f(H3[(size_t)s0 * 64 + lane]);
    float h1 = bf2f(H3[(size_t)s1 * 64 + lane]);
    float h2 = bf2f(H3[(size_t)s2 * 64 + lane]);
    float h3 = bf2f(H3[(size_t)s3 * 64 + lane]);
    float h4 = bf2f(H3[(size_t)s4 * 64 + lane]);
    float h5 = bf2f(H3[(size_t)s5 * 64 + lane]);
    float h6 = bf2f(H3[(size_t)s6 * 64 + lane]);
    float h7 = bf2f(H3[(size_t)s7 * 64 + lane]);
    acc += h0 + h1 + h2 + h3 + h4 + h5 + h6 + h7;
  }
  for (; j < je; ++j) acc += bf2f(H3[(size_t)ssrc[j] * 64 + lane]);
  out[(size_t)n * 64 + lane] = fmaxf(fmaf(dn, acc, b2[lane]), 0.f);
}

extern "C" void kernel_launch(void* const* d_in, const int* in_sizes, int n_in,
                              void* d_out, int out_size, void* d_ws, size_t ws_size,
                              hipStream_t stream) {
  const float* x  = (const float*)d_in[0];
  const int*   ei = (const int*)d_in[1];
  const float* W1 = (const float*)d_in[2];
  const float* b1 = (const float*)d_in[3];
  const float* W2 = (const float*)d_in[4];
  const float* b2 = (const float*)d_in[5];
  const int* esrc = ei;
  const int* edst = ei + NE;

  char* ws = (char*)d_ws;
  unsigned* gcur  = (unsigned*)(ws + 0);
  int*      off   = (int*)(ws + 2048);
  float*    dinv  = (float*)(ws + 204800);
  unsigned short* ssrc = (unsigned short*)(ws + 405504);   // 1.6 MB
  unsigned short* W1T  = (unsigned short*)(ws + 2013184);  // 32 KB
  unsigned short* W2T  = (unsigned short*)(ws + 2045952);  // 16 KB
  unsigned* part  = (unsigned*)(ws + 2097152);             // ~4 MB
  unsigned* Hb    = (unsigned*)(ws + 6291456);             // 12.8 MB
  unsigned* H2    = (unsigned*)(ws + 19922944);            // 12.8 MB
  unsigned short* H3 = (unsigned short*)(ws + 33554432);   // 6.4 MB

  hipLaunchKernelGGL(k_prep, dim3(64), dim3(256), 0, stream, W1, W2, W1T, W2T, gcur);
  hipLaunchKernelGGL(k_partmm1, dim3(NPART + (NN + 63) / 64), dim3(256), 0, stream,
                     esrc, edst, gcur, part, x, W1T, Hb);
  hipLaunchKernelGGL(k_bucket, dim3(NBUCK), dim3(256), 0, stream,
                     gcur, part, off, dinv, ssrc);
  hipLaunchKernelGGL(k_agg1, dim3((NN + 3) / 4), dim3(256), 0, stream,
                     Hb, off, ssrc, dinv, b1, H2);
  hipLaunchKernelGGL(k_mm2, dim3((NN + 63) / 64), dim3(256), 0, stream,
                     H2, W2T, dinv, (unsigned*)H3);
  hipLaunchKernelGGL(k_agg2, dim3((NN + 3) / 4), dim3(256), 0, stream,
                     H3, off, ssrc, dinv, b2, (float*)d_out);
}

// Round 15
// 105.610 us; speedup vs baseline: 2.3363x; 1.1276x over previous
//
#include <hip/hip_runtime.h>

#define NN 50000
#define NE 800000
#define NBUCK 196        // coarse buckets: dst>>8
#define BCAP 5120
#define NPART 256
#define EPP (NE / NPART) // 3125

typedef short short8 __attribute__((ext_vector_type(8)));
typedef float f32x4 __attribute__((ext_vector_type(4)));
union U4 { uint4 u; short8 h; };

__device__ __forceinline__ unsigned f2bf(float f) {
  union { float f; unsigned u; } v; v.f = f;
  return (v.u + 0x7FFFu + ((v.u >> 16) & 1u)) >> 16;
}
__device__ __forceinline__ float2 upk(unsigned u) {
  union { unsigned u; float f; } a, b;
  a.u = u << 16; b.u = u & 0xFFFF0000u;
  return make_float2(a.f, b.f);
}
__device__ __forceinline__ float bf2f(unsigned short b) {
  union { unsigned u; float f; } v; v.u = ((unsigned)b) << 16;
  return v.f;
}
__device__ __forceinline__ unsigned pk2(float a, float b) {
  return f2bf(a) | (f2bf(b) << 16);
}

// ---------------- prep: W1T/W2T bf16 transposed+swizzled; zeros gcur ----------------
__global__ __launch_bounds__(256) void k_prep(const float* __restrict__ W1,
                                              const float* __restrict__ W2,
                                              unsigned short* __restrict__ W1T,
                                              unsigned short* __restrict__ W2T,
                                              unsigned* __restrict__ gcur) {
  int b = blockIdx.x, t = threadIdx.x;
  if (b == 0 && t < NBUCK) gcur[t] = 0;
  {
    int idx = b * 256 + t;
    int k = idx >> 7, n = idx & 127;
    W1T[(n << 7) + (k ^ ((n & 7) << 3))] = (unsigned short)f2bf(W1[idx]);
  }
  if (t < 128) {
    int idx = b * 128 + t;
    int k = idx >> 6, n = idx & 63;
    W2T[(n << 7) + (k ^ ((n & 7) << 3))] = (unsigned short)f2bf(W2[idx]);
  }
}

// ---------------- Phase A partition (blocks 0..255) + MFMA GEMM-1 (blocks 256..) ----------------
__global__ __launch_bounds__(256) void k_partmm1(const int* __restrict__ src,
                                                 const int* __restrict__ dst,
                                                 unsigned* __restrict__ gcur,
                                                 unsigned* __restrict__ part,
                                                 const float* __restrict__ X,
                                                 const unsigned short* __restrict__ W1T,
                                                 unsigned* __restrict__ Hbu) {
  __shared__ __attribute__((aligned(16))) unsigned smem[12288];  // 48 KB
  __shared__ int wsum[4];
  const int tid = threadIdx.x;
  if (blockIdx.x < NPART) {
    unsigned* stage = smem;
    unsigned* hist  = smem + 3200;
    unsigned* curs  = smem + 3400;
    unsigned* bbs   = smem + 3600;
    const int e0 = blockIdx.x * EPP;
    for (int i = tid; i < NBUCK; i += 256) hist[i] = 0;
    __syncthreads();
    for (int k = tid; k < EPP; k += 256)
      atomicAdd(&hist[((unsigned)dst[e0 + k]) >> 8], 1u);
    __syncthreads();
    {
      int lane = tid & 63, w = tid >> 6;
      unsigned v = (tid < NBUCK) ? hist[tid] : 0;
      unsigned incl = v;
#pragma unroll
      for (int d = 1; d < 64; d <<= 1) {
        unsigned u = __shfl_up(incl, d);
        if (lane >= d) incl += u;
      }
      if (lane == 63) wsum[w] = (int)incl;
      __syncthreads();
      unsigned wpre = 0;
      for (int j = 0; j < w; ++j) wpre += (unsigned)wsum[j];
      if (tid < NBUCK) curs[tid] = wpre + incl - v;
    }
    __syncthreads();
    for (int k = tid; k < EPP; k += 256) {
      int d = dst[e0 + k];
      unsigned slot = atomicAdd(&curs[((unsigned)d) >> 8], 1u);
      stage[slot] = (((unsigned)src[e0 + k]) << 16) | (unsigned)d;
    }
    __syncthreads();
    if (tid < NBUCK) bbs[tid] = atomicAdd(&gcur[tid], hist[tid]);
    __syncthreads();
    for (int k = tid; k < EPP; k += 256) {
      unsigned v = stage[k];
      unsigned b = (v & 0xFFFFu) >> 8;
      unsigned startb = curs[b] - hist[b];
      part[b * BCAP + bbs[b] + ((unsigned)k - startb)] = v;
    }
  } else {
    uint4* w1t4 = (uint4*)smem;
    uint4* xs4  = (uint4*)(smem + 8192);
    const int base = (blockIdx.x - NPART) * 64;
    const uint4* W1Tg = (const uint4*)W1T;
    const float4* X4 = (const float4*)X;
#pragma unroll
    for (int it = 0; it < 8; ++it) w1t4[tid + 256 * it] = W1Tg[tid + 256 * it];
#pragma unroll
    for (int it = 0; it < 4; ++it) {
      int j = tid + 256 * it;
      int row = j >> 4, c16 = j & 15;
      int grow = base + row;
      uint4 v = make_uint4(0, 0, 0, 0);
      if (grow < NN) {
        float4 f0 = X4[(size_t)grow * 32 + c16 * 2];
        float4 f1 = X4[(size_t)grow * 32 + c16 * 2 + 1];
        v = make_uint4(pk2(f0.x, f0.y), pk2(f0.z, f0.w), pk2(f1.x, f1.y), pk2(f1.z, f1.w));
      }
      xs4[row * 16 + (c16 ^ (row & 7))] = v;
    }
    __syncthreads();
    const int lane = tid & 63, wv = tid >> 6;
    const int l7 = lane & 7, lg = lane >> 4;
    f32x4 acc[8];
#pragma unroll
    for (int c = 0; c < 8; ++c) acc[c] = (f32x4){0.f, 0.f, 0.f, 0.f};
    const int arow = wv * 16 + (lane & 15);
#pragma unroll
    for (int kk = 0; kk < 4; ++kk) {
      int kcc = kk * 4 + lg;
      U4 a; a.u = xs4[arow * 16 + (kcc ^ l7)];
#pragma unroll
      for (int c = 0; c < 8; ++c) {
        int n = c * 16 + (lane & 15);
        U4 b; b.u = w1t4[n * 16 + (kcc ^ l7)];
        acc[c] = __builtin_amdgcn_mfma_f32_16x16x32_bf16(a.h, b.h, acc[c], 0, 0, 0);
      }
    }
#pragma unroll
    for (int c = 0; c < 8; ++c) {
#pragma unroll
      for (int r = 0; r < 4; ++r) {
        int grow = base + wv * 16 + lg * 4 + r;
        unsigned mb = f2bf(acc[c][r]);
        unsigned ob = (unsigned)__shfl_xor((int)mb, 1);
        if (((lane & 1) == 0) && grow < NN)
          Hbu[(size_t)grow * 64 + c * 8 + ((lane & 15) >> 1)] = mb | (ob << 16);
      }
    }
  }
}

// ---------------- Phase B: per-bucket bin sort (fused base-scan) -> off, dinv, ssrc ----------------
__global__ __launch_bounds__(256) void k_bucket(const unsigned* __restrict__ gcur,
                                                const unsigned* __restrict__ part,
                                                int* __restrict__ off,
                                                float* __restrict__ dinv,
                                                unsigned short* __restrict__ ssrc) {
  __shared__ unsigned hist[256], curs[256], sb[256];
  __shared__ unsigned short ssr[BCAP];
  __shared__ int wsum[4];
  const int tid = threadIdx.x, b = blockIdx.x;
  const int lane = tid & 63, w = tid >> 6;
  {
    unsigned g = (tid < NBUCK) ? gcur[tid] : 0;
    unsigned incl = g;
#pragma unroll
    for (int d = 1; d < 64; d <<= 1) {
      unsigned u = __shfl_up(incl, d);
      if (lane >= d) incl += u;
    }
    if (lane == 63) wsum[w] = (int)incl;
    __syncthreads();
    unsigned wpre = 0;
    for (int j = 0; j < w; ++j) wpre += (unsigned)wsum[j];
    sb[tid] = wpre + incl - g;
  }
  __syncthreads();
  const int nb = (int)gcur[b];
  const int base = (int)sb[b];
  const unsigned* pp = part + (size_t)b * BCAP;
  hist[tid] = 0;
  __syncthreads();
  for (int k = tid; k < nb; k += 256) atomicAdd(&hist[pp[k] & 255u], 1u);
  __syncthreads();
  unsigned v = hist[tid];
  unsigned incl = v;
#pragma unroll
  for (int d = 1; d < 64; d <<= 1) {
    unsigned u = __shfl_up(incl, d);
    if (lane >= d) incl += u;
  }
  if (lane == 63) wsum[w] = (int)incl;
  __syncthreads();
  unsigned wpre = 0;
  for (int j = 0; j < w; ++j) wpre += (unsigned)wsum[j];
  unsigned excl = wpre + incl - v;
  curs[tid] = excl;
  int node = b * 256 + tid;
  if (node < NN) {
    off[node] = base + (int)excl;
    dinv[node] = rsqrtf((float)(v + 1));
  } else if (node == NN) {
    off[NN] = base + (int)excl;
  }
  __syncthreads();
  for (int k = tid; k < nb; k += 256) {
    unsigned vv = pp[k];
    unsigned slot = atomicAdd(&curs[vv & 255u], 1u);
    ssr[slot] = (unsigned short)(vv >> 16);
  }
  __syncthreads();
  for (int k = tid; k < nb; k += 256) ssrc[base + k] = ssr[k];
}

// ---------------- agg1: half-wave 2-edge scheme; uint2 (8B) loads; 2x lines in flight ----------------
__global__ __launch_bounds__(256) void k_agg1(const unsigned* __restrict__ Hb,
                                              const int* __restrict__ off,
                                              const unsigned short* __restrict__ ssrc,
                                              const float* __restrict__ dinv,
                                              const float* __restrict__ b1,
                                              unsigned* __restrict__ H2) {
  int n = (blockIdx.x * 256 + threadIdx.x) >> 6;
  int lane = threadIdx.x & 63;
  if (n >= NN) return;
  const int half = lane >> 5, hl = lane & 31;
  const uint2* Hb2 = (const uint2*)Hb;
  float dn = dinv[n];
  int jb = off[n], je = off[n + 1];
  f32x4 acc = (f32x4){0.f, 0.f, 0.f, 0.f};
  if (half == 0) {  // self term in half 0
    uint2 u = Hb2[(size_t)n * 32 + hl];
    float2 a = upk(u.x), b = upk(u.y);
    acc[0] = dn * a.x; acc[1] = dn * a.y; acc[2] = dn * b.x; acc[3] = dn * b.y;
  }
  int j = jb;
  for (; j + 15 < je; j += 16) {  // 8 edges per half
    int s[8]; float wgt[8]; uint2 u[8];
#pragma unroll
    for (int k = 0; k < 8; ++k) s[k] = ssrc[j + 2 * k + half];
#pragma unroll
    for (int k = 0; k < 8; ++k) wgt[k] = dinv[s[k]];
#pragma unroll
    for (int k = 0; k < 8; ++k) u[k] = Hb2[(size_t)s[k] * 32 + hl];
#pragma unroll
    for (int k = 0; k < 8; ++k) {
      float2 a = upk(u[k].x), b = upk(u[k].y);
      acc[0] = fmaf(a.x, wgt[k], acc[0]);
      acc[1] = fmaf(a.y, wgt[k], acc[1]);
      acc[2] = fmaf(b.x, wgt[k], acc[2]);
      acc[3] = fmaf(b.y, wgt[k], acc[3]);
    }
  }
  for (; j + 7 < je; j += 8) {  // 4 edges per half
    int s[4]; float wgt[4]; uint2 u[4];
#pragma unroll
    for (int k = 0; k < 4; ++k) s[k] = ssrc[j + 2 * k + half];
#pragma unroll
    for (int k = 0; k < 4; ++k) wgt[k] = dinv[s[k]];
#pragma unroll
    for (int k = 0; k < 4; ++k) u[k] = Hb2[(size_t)s[k] * 32 + hl];
#pragma unroll
    for (int k = 0; k < 4; ++k) {
      float2 a = upk(u[k].x), b = upk(u[k].y);
      acc[0] = fmaf(a.x, wgt[k], acc[0]);
      acc[1] = fmaf(a.y, wgt[k], acc[1]);
      acc[2] = fmaf(b.x, wgt[k], acc[2]);
      acc[3] = fmaf(b.y, wgt[k], acc[3]);
    }
  }
  for (; j + 1 < je; j += 2) {  // 1 edge per half
    int s0 = ssrc[j + half];
    float w0 = dinv[s0];
    uint2 u = Hb2[(size_t)s0 * 32 + hl];
    float2 a = upk(u.x), b = upk(u.y);
    acc[0] = fmaf(a.x, w0, acc[0]);
    acc[1] = fmaf(a.y, w0, acc[1]);
    acc[2] = fmaf(b.x, w0, acc[2]);
    acc[3] = fmaf(b.y, w0, acc[3]);
  }
  if (j < je && half == 0) {  // final odd edge
    int s0 = ssrc[j];
    float w0 = dinv[s0];
    uint2 u = Hb2[(size_t)s0 * 32 + hl];
    float2 a = upk(u.x), b = upk(u.y);
    acc[0] = fmaf(a.x, w0, acc[0]);
    acc[1] = fmaf(a.y, w0, acc[1]);
    acc[2] = fmaf(b.x, w0, acc[2]);
    acc[3] = fmaf(b.y, w0, acc[3]);
  }
  // combine halves
#pragma unroll
  for (int k = 0; k < 4; ++k) acc[k] += __shfl_xor(acc[k], 32);
  if (half == 0) {
    float4 bb = ((const float4*)b1)[hl];
    float h0 = fmaxf(fmaf(dn, acc[0], bb.x), 0.f);
    float h1 = fmaxf(fmaf(dn, acc[1], bb.y), 0.f);
    float h2 = fmaxf(fmaf(dn, acc[2], bb.z), 0.f);
    float h3 = fmaxf(fmaf(dn, acc[3], bb.w), 0.f);
    ((uint2*)H2)[(size_t)n * 32 + hl] = make_uint2(pk2(h0, h1), pk2(h2, h3));
  }
}

// ---------------- MFMA GEMM-2: 64 rows x 64 cols per block ----------------
__global__ __launch_bounds__(256) void k_mm2(const unsigned* __restrict__ H2,
                                             const unsigned short* __restrict__ W2T,
                                             const float* __restrict__ dinv,
                                             unsigned* __restrict__ H3u) {
  __shared__ __attribute__((aligned(16))) unsigned smem[8192];
  uint4* w2t4 = (uint4*)smem;
  uint4* xs4  = (uint4*)(smem + 4096);
  const int tid = threadIdx.x;
  const int base = blockIdx.x * 64;
  const uint4* W2Tg = (const uint4*)W2T;
  const uint4* H2v = (const uint4*)H2;
#pragma unroll
  for (int it = 0; it < 4; ++it) w2t4[tid + 256 * it] = W2Tg[tid + 256 * it];
#pragma unroll
  for (int it = 0; it < 4; ++it) {
    int j = tid + 256 * it;
    int row = j >> 4, c16 = j & 15;
    int grow = base + row;
    uint4 v = (grow < NN) ? H2v[(size_t)grow * 16 + c16] : make_uint4(0, 0, 0, 0);
    xs4[row * 16 + (c16 ^ (row & 7))] = v;
  }
  __syncthreads();
  const int lane = tid & 63, wv = tid >> 6;
  const int l7 = lane & 7, lg = lane >> 4;
  f32x4 acc[4];
#pragma unroll
  for (int c = 0; c < 4; ++c) acc[c] = (f32x4){0.f, 0.f, 0.f, 0.f};
  const int arow = wv * 16 + (lane & 15);
#pragma unroll
  for (int kk = 0; kk < 4; ++kk) {
    int kcc = kk * 4 + lg;
    U4 a; a.u = xs4[arow * 16 + (kcc ^ l7)];
#pragma unroll
    for (int c = 0; c < 4; ++c) {
      int n = c * 16 + (lane & 15);
      U4 b; b.u = w2t4[n * 16 + (kcc ^ l7)];
      acc[c] = __builtin_amdgcn_mfma_f32_16x16x32_bf16(a.h, b.h, acc[c], 0, 0, 0);
    }
  }
#pragma unroll
  for (int c = 0; c < 4; ++c) {
#pragma unroll
    for (int r = 0; r < 4; ++r) {
      int grow = base + wv * 16 + lg * 4 + r;
      float dn = (grow < NN) ? dinv[grow] : 0.f;
      unsigned mb = f2bf(acc[c][r] * dn);
      unsigned ob = (unsigned)__shfl_xor((int)mb, 1);
      if (((lane & 1) == 0) && grow < NN)
        H3u[(size_t)grow * 32 + c * 8 + ((lane & 15) >> 1)] = mb | (ob << 16);
    }
  }
}

// ---------------- agg2: half-wave 2-edge scheme; u32 (4B) loads; 2x lines in flight ----------------
__global__ __launch_bounds__(256) void k_agg2(const unsigned* __restrict__ H3u,
                                              const int* __restrict__ off,
                                              const unsigned short* __restrict__ ssrc,
                                              const float* __restrict__ dinv,
                                              const float* __restrict__ b2,
                                              float* __restrict__ out) {
  int n = (blockIdx.x * 256 + threadIdx.x) >> 6;
  int lane = threadIdx.x & 63;
  if (n >= NN) return;
  const int half = lane >> 5, hl = lane & 31;
  float dn = dinv[n];
  int jb = off[n], je = off[n + 1];
  float2 acc = make_float2(0.f, 0.f);
  if (half == 0) {  // self term (H3 prescaled)
    float2 f = upk(H3u[(size_t)n * 32 + hl]);
    acc = f;
  }
  int j = jb;
  for (; j + 15 < je; j += 16) {  // 8 edges per half
    int s[8]; unsigned u[8];
#pragma unroll
    for (int k = 0; k < 8; ++k) s[k] = ssrc[j + 2 * k + half];
#pragma unroll
    for (int k = 0; k < 8; ++k) u[k] = H3u[(size_t)s[k] * 32 + hl];
#pragma unroll
    for (int k = 0; k < 8; ++k) {
      float2 f = upk(u[k]);
      acc.x += f.x; acc.y += f.y;
    }
  }
  for (; j + 7 < je; j += 8) {  // 4 edges per half
    int s[4]; unsigned u[4];
#pragma unroll
    for (int k = 0; k < 4; ++k) s[k] = ssrc[j + 2 * k + half];
#pragma unroll
    for (int k = 0; k < 4; ++k) u[k] = H3u[(size_t)s[k] * 32 + hl];
#pragma unroll
    for (int k = 0; k < 4; ++k) {
      float2 f = upk(u[k]);
      acc.x += f.x; acc.y += f.y;
    }
  }
  for (; j + 1 < je; j += 2) {  // 1 edge per half
    float2 f = upk(H3u[(size_t)ssrc[j + half] * 32 + hl]);
    acc.x += f.x; acc.y += f.y;
  }
  if (j < je && half == 0) {  // final odd edge
    float2 f = upk(H3u[(size_t)ssrc[j] * 32 + hl]);
    acc.x += f.x; acc.y += f.y;
  }
  acc.x += __shfl_xor(acc.x, 32);
  acc.y += __shfl_xor(acc.y, 32);
  if (half == 0) {
    float2 bb = ((const float2*)b2)[hl];
    ((float2*)out)[(size_t)n * 32 + hl] =
        make_float2(fmaxf(fmaf(dn, acc.x, bb.x), 0.f),
                    fmaxf(fmaf(dn, acc.y, bb.y), 0.f));
  }
}

extern "C" void kernel_launch(void* const* d_in, const int* in_sizes, int n_in,
                              void* d_out, int out_size, void* d_ws, size_t ws_size,
                              hipStream_t stream) {
  const float* x  = (const float*)d_in[0];
  const int*   ei = (const int*)d_in[1];
  const float* W1 = (const float*)d_in[2];
  const float* b1 = (const float*)d_in[3];
  const float* W2 = (const float*)d_in[4];
  const float* b2 = (const float*)d_in[5];
  const int* esrc = ei;
  const int* edst = ei + NE;

  char* ws = (char*)d_ws;
  unsigned* gcur  = (unsigned*)(ws + 0);
  int*      off   = (int*)(ws + 2048);
  float*    dinv  = (float*)(ws + 204800);
  unsigned short* ssrc = (unsigned short*)(ws + 405504);   // 1.6 MB
  unsigned short* W1T  = (unsigned short*)(ws + 2013184);  // 32 KB
  unsigned short* W2T  = (unsigned short*)(ws + 2045952);  // 16 KB
  unsigned* part  = (unsigned*)(ws + 2097152);             // ~4 MB
  unsigned* Hb    = (unsigned*)(ws + 6291456);             // 12.8 MB
  unsigned* H2    = (unsigned*)(ws + 19922944);            // 12.8 MB
  unsigned* H3    = (unsigned*)(ws + 33554432);            // 6.4 MB

  hipLaunchKernelGGL(k_prep, dim3(64), dim3(256), 0, stream, W1, W2, W1T, W2T, gcur);
  hipLaunchKernelGGL(k_partmm1, dim3(NPART + (NN + 63) / 64), dim3(256), 0, stream,
                     esrc, edst, gcur, part, x, W1T, Hb);
  hipLaunchKernelGGL(k_bucket, dim3(NBUCK), dim3(256), 0, stream,
                     gcur, part, off, dinv, ssrc);
  hipLaunchKernelGGL(k_agg1, dim3((NN + 3) / 4), dim3(256), 0, stream,
                     Hb, off, ssrc, dinv, b1, H2);
  hipLaunchKernelGGL(k_mm2, dim3((NN + 63) / 64), dim3(256), 0, stream,
                     H2, W2T, dinv, H3);
  hipLaunchKernelGGL(k_agg2, dim3((NN + 3) / 4), dim3(256), 0, stream,
                     H3, off, ssrc, dinv, b2, (float*)d_out);
}

// Round 16
// 100.906 us; speedup vs baseline: 2.4453x; 1.0466x over previous
//
#include <hip/hip_runtime.h>

#define NN 50000
#define NE 800000
#define NBUCK 196        // coarse buckets: dst>>8
#define BCAP 5120
#define NPART 256
#define EPP (NE / NPART) // 3125

typedef short short8 __attribute__((ext_vector_type(8)));
typedef float f32x4 __attribute__((ext_vector_type(4)));
union U4 { uint4 u; short8 h; };

__device__ __forceinline__ unsigned f2bf(float f) {
  union { float f; unsigned u; } v; v.f = f;
  return (v.u + 0x7FFFu + ((v.u >> 16) & 1u)) >> 16;
}
__device__ __forceinline__ float2 upk(unsigned u) {
  union { unsigned u; float f; } a, b;
  a.u = u << 16; b.u = u & 0xFFFF0000u;
  return make_float2(a.f, b.f);
}
__device__ __forceinline__ unsigned pk2(float a, float b) {
  return f2bf(a) | (f2bf(b) << 16);
}

// ---------------- prep: W1T/W2T bf16 transposed+swizzled; zeros gcur ----------------
__global__ __launch_bounds__(256) void k_prep(const float* __restrict__ W1,
                                              const float* __restrict__ W2,
                                              unsigned short* __restrict__ W1T,
                                              unsigned short* __restrict__ W2T,
                                              unsigned* __restrict__ gcur) {
  int b = blockIdx.x, t = threadIdx.x;
  if (b == 0 && t < NBUCK) gcur[t] = 0;
  {
    int idx = b * 256 + t;
    int k = idx >> 7, n = idx & 127;
    W1T[(n << 7) + (k ^ ((n & 7) << 3))] = (unsigned short)f2bf(W1[idx]);
  }
  if (t < 128) {
    int idx = b * 128 + t;
    int k = idx >> 6, n = idx & 63;
    W2T[(n << 7) + (k ^ ((n & 7) << 3))] = (unsigned short)f2bf(W2[idx]);
  }
}

// ---------------- Phase A partition (blocks 0..255) + MFMA GEMM-1 (blocks 256..) ----------------
__global__ __launch_bounds__(256) void k_partmm1(const int* __restrict__ src,
                                                 const int* __restrict__ dst,
                                                 unsigned* __restrict__ gcur,
                                                 unsigned* __restrict__ part,
                                                 const float* __restrict__ X,
                                                 const unsigned short* __restrict__ W1T,
                                                 unsigned* __restrict__ Hbu) {
  __shared__ __attribute__((aligned(16))) unsigned smem[12288];  // 48 KB
  __shared__ int wsum[4];
  const int tid = threadIdx.x;
  if (blockIdx.x < NPART) {
    unsigned* stage = smem;
    unsigned* hist  = smem + 3200;
    unsigned* curs  = smem + 3400;
    unsigned* bbs   = smem + 3600;
    const int e0 = blockIdx.x * EPP;
    for (int i = tid; i < NBUCK; i += 256) hist[i] = 0;
    __syncthreads();
    for (int k = tid; k < EPP; k += 256)
      atomicAdd(&hist[((unsigned)dst[e0 + k]) >> 8], 1u);
    __syncthreads();
    {
      int lane = tid & 63, w = tid >> 6;
      unsigned v = (tid < NBUCK) ? hist[tid] : 0;
      unsigned incl = v;
#pragma unroll
      for (int d = 1; d < 64; d <<= 1) {
        unsigned u = __shfl_up(incl, d);
        if (lane >= d) incl += u;
      }
      if (lane == 63) wsum[w] = (int)incl;
      __syncthreads();
      unsigned wpre = 0;
      for (int j = 0; j < w; ++j) wpre += (unsigned)wsum[j];
      if (tid < NBUCK) curs[tid] = wpre + incl - v;
    }
    __syncthreads();
    for (int k = tid; k < EPP; k += 256) {
      int d = dst[e0 + k];
      unsigned slot = atomicAdd(&curs[((unsigned)d) >> 8], 1u);
      stage[slot] = (((unsigned)src[e0 + k]) << 16) | (unsigned)d;
    }
    __syncthreads();
    if (tid < NBUCK) bbs[tid] = atomicAdd(&gcur[tid], hist[tid]);
    __syncthreads();
    for (int k = tid; k < EPP; k += 256) {
      unsigned v = stage[k];
      unsigned b = (v & 0xFFFFu) >> 8;
      unsigned startb = curs[b] - hist[b];
      part[b * BCAP + bbs[b] + ((unsigned)k - startb)] = v;
    }
  } else {
    uint4* w1t4 = (uint4*)smem;
    uint4* xs4  = (uint4*)(smem + 8192);
    const int base = (blockIdx.x - NPART) * 64;
    const uint4* W1Tg = (const uint4*)W1T;
    const float4* X4 = (const float4*)X;
#pragma unroll
    for (int it = 0; it < 8; ++it) w1t4[tid + 256 * it] = W1Tg[tid + 256 * it];
#pragma unroll
    for (int it = 0; it < 4; ++it) {
      int j = tid + 256 * it;
      int row = j >> 4, c16 = j & 15;
      int grow = base + row;
      uint4 v = make_uint4(0, 0, 0, 0);
      if (grow < NN) {
        float4 f0 = X4[(size_t)grow * 32 + c16 * 2];
        float4 f1 = X4[(size_t)grow * 32 + c16 * 2 + 1];
        v = make_uint4(pk2(f0.x, f0.y), pk2(f0.z, f0.w), pk2(f1.x, f1.y), pk2(f1.z, f1.w));
      }
      xs4[row * 16 + (c16 ^ (row & 7))] = v;
    }
    __syncthreads();
    const int lane = tid & 63, wv = tid >> 6;
    const int l7 = lane & 7, lg = lane >> 4;
    f32x4 acc[8];
#pragma unroll
    for (int c = 0; c < 8; ++c) acc[c] = (f32x4){0.f, 0.f, 0.f, 0.f};
    const int arow = wv * 16 + (lane & 15);
#pragma unroll
    for (int kk = 0; kk < 4; ++kk) {
      int kcc = kk * 4 + lg;
      U4 a; a.u = xs4[arow * 16 + (kcc ^ l7)];
#pragma unroll
      for (int c = 0; c < 8; ++c) {
        int n = c * 16 + (lane & 15);
        U4 b; b.u = w1t4[n * 16 + (kcc ^ l7)];
        acc[c] = __builtin_amdgcn_mfma_f32_16x16x32_bf16(a.h, b.h, acc[c], 0, 0, 0);
      }
    }
#pragma unroll
    for (int c = 0; c < 8; ++c) {
#pragma unroll
      for (int r = 0; r < 4; ++r) {
        int grow = base + wv * 16 + lg * 4 + r;
        unsigned mb = f2bf(acc[c][r]);
        unsigned ob = (unsigned)__shfl_xor((int)mb, 1);
        if (((lane & 1) == 0) && grow < NN)
          Hbu[(size_t)grow * 64 + c * 8 + ((lane & 15) >> 1)] = mb | (ob << 16);
      }
    }
  }
}

// ---------------- Phase B: per-bucket bin sort (fused base-scan) -> off, dinv, ssrc ----------------
__global__ __launch_bounds__(256) void k_bucket(const unsigned* __restrict__ gcur,
                                                const unsigned* __restrict__ part,
                                                int* __restrict__ off,
                                                float* __restrict__ dinv,
                                                unsigned short* __restrict__ ssrc) {
  __shared__ unsigned hist[256], curs[256], sb[256];
  __shared__ unsigned short ssr[BCAP];
  __shared__ int wsum[4];
  const int tid = threadIdx.x, b = blockIdx.x;
  const int lane = tid & 63, w = tid >> 6;
  {
    unsigned g = (tid < NBUCK) ? gcur[tid] : 0;
    unsigned incl = g;
#pragma unroll
    for (int d = 1; d < 64; d <<= 1) {
      unsigned u = __shfl_up(incl, d);
      if (lane >= d) incl += u;
    }
    if (lane == 63) wsum[w] = (int)incl;
    __syncthreads();
    unsigned wpre = 0;
    for (int j = 0; j < w; ++j) wpre += (unsigned)wsum[j];
    sb[tid] = wpre + incl - g;
  }
  __syncthreads();
  const int nb = (int)gcur[b];
  const int base = (int)sb[b];
  const unsigned* pp = part + (size_t)b * BCAP;
  hist[tid] = 0;
  __syncthreads();
  for (int k = tid; k < nb; k += 256) atomicAdd(&hist[pp[k] & 255u], 1u);
  __syncthreads();
  unsigned v = hist[tid];
  unsigned incl = v;
#pragma unroll
  for (int d = 1; d < 64; d <<= 1) {
    unsigned u = __shfl_up(incl, d);
    if (lane >= d) incl += u;
  }
  if (lane == 63) wsum[w] = (int)incl;
  __syncthreads();
  unsigned wpre = 0;
  for (int j = 0; j < w; ++j) wpre += (unsigned)wsum[j];
  unsigned excl = wpre + incl - v;
  curs[tid] = excl;
  int node = b * 256 + tid;
  if (node < NN) {
    off[node] = base + (int)excl;
    dinv[node] = rsqrtf((float)(v + 1));
  } else if (node == NN) {
    off[NN] = base + (int)excl;
  }
  __syncthreads();
  for (int k = tid; k < nb; k += 256) {
    unsigned vv = pp[k];
    unsigned slot = atomicAdd(&curs[vv & 255u], 1u);
    ssr[slot] = (unsigned short)(vv >> 16);
  }
  __syncthreads();
  for (int k = tid; k < nb; k += 256) ssrc[base + k] = ssr[k];
}

// ---------------- agg1: quarter-wave (16 lanes/edge, uint4 16B loads) ----------------
__global__ __launch_bounds__(256) void k_agg1(const unsigned* __restrict__ Hb,
                                              const int* __restrict__ off,
                                              const unsigned short* __restrict__ ssrc,
                                              const float* __restrict__ dinv,
                                              const float* __restrict__ b1,
                                              unsigned* __restrict__ H2) {
  int n = (blockIdx.x * 256 + threadIdx.x) >> 6;
  int lane = threadIdx.x & 63;
  if (n >= NN) return;
  const int q = lane >> 4, ql = lane & 15;
  const uint4* Hb4 = (const uint4*)Hb;
  float dn = dinv[n];
  int jb = off[n], je = off[n + 1];
  float acc[8] = {0.f, 0.f, 0.f, 0.f, 0.f, 0.f, 0.f, 0.f};
  if (q == 0) {  // self term
    uint4 u = Hb4[(size_t)n * 16 + ql];
    float2 a0 = upk(u.x), a1 = upk(u.y), a2 = upk(u.z), a3 = upk(u.w);
    acc[0] = dn * a0.x; acc[1] = dn * a0.y; acc[2] = dn * a1.x; acc[3] = dn * a1.y;
    acc[4] = dn * a2.x; acc[5] = dn * a2.y; acc[6] = dn * a3.x; acc[7] = dn * a3.y;
  }
  int j = jb;
  for (; j + 15 < je; j += 16) {  // 4 edges per quarter
    int s[4]; float wgt[4]; uint4 u[4];
#pragma unroll
    for (int k = 0; k < 4; ++k) s[k] = ssrc[j + 4 * k + q];
#pragma unroll
    for (int k = 0; k < 4; ++k) wgt[k] = dinv[s[k]];
#pragma unroll
    for (int k = 0; k < 4; ++k) u[k] = Hb4[(size_t)s[k] * 16 + ql];
#pragma unroll
    for (int k = 0; k < 4; ++k) {
      float2 a0 = upk(u[k].x), a1 = upk(u[k].y), a2 = upk(u[k].z), a3 = upk(u[k].w);
      acc[0] = fmaf(a0.x, wgt[k], acc[0]); acc[1] = fmaf(a0.y, wgt[k], acc[1]);
      acc[2] = fmaf(a1.x, wgt[k], acc[2]); acc[3] = fmaf(a1.y, wgt[k], acc[3]);
      acc[4] = fmaf(a2.x, wgt[k], acc[4]); acc[5] = fmaf(a2.y, wgt[k], acc[5]);
      acc[6] = fmaf(a3.x, wgt[k], acc[6]); acc[7] = fmaf(a3.y, wgt[k], acc[7]);
    }
  }
  for (; j + 7 < je; j += 8) {  // 2 edges per quarter
    int s[2]; float wgt[2]; uint4 u[2];
#pragma unroll
    for (int k = 0; k < 2; ++k) s[k] = ssrc[j + 4 * k + q];
#pragma unroll
    for (int k = 0; k < 2; ++k) wgt[k] = dinv[s[k]];
#pragma unroll
    for (int k = 0; k < 2; ++k) u[k] = Hb4[(size_t)s[k] * 16 + ql];
#pragma unroll
    for (int k = 0; k < 2; ++k) {
      float2 a0 = upk(u[k].x), a1 = upk(u[k].y), a2 = upk(u[k].z), a3 = upk(u[k].w);
      acc[0] = fmaf(a0.x, wgt[k], acc[0]); acc[1] = fmaf(a0.y, wgt[k], acc[1]);
      acc[2] = fmaf(a1.x, wgt[k], acc[2]); acc[3] = fmaf(a1.y, wgt[k], acc[3]);
      acc[4] = fmaf(a2.x, wgt[k], acc[4]); acc[5] = fmaf(a2.y, wgt[k], acc[5]);
      acc[6] = fmaf(a3.x, wgt[k], acc[6]); acc[7] = fmaf(a3.y, wgt[k], acc[7]);
    }
  }
  for (; j + 3 < je; j += 4) {  // 1 edge per quarter
    int s0 = ssrc[j + q];
    float w0 = dinv[s0];
    uint4 u = Hb4[(size_t)s0 * 16 + ql];
    float2 a0 = upk(u.x), a1 = upk(u.y), a2 = upk(u.z), a3 = upk(u.w);
    acc[0] = fmaf(a0.x, w0, acc[0]); acc[1] = fmaf(a0.y, w0, acc[1]);
    acc[2] = fmaf(a1.x, w0, acc[2]); acc[3] = fmaf(a1.y, w0, acc[3]);
    acc[4] = fmaf(a2.x, w0, acc[4]); acc[5] = fmaf(a2.y, w0, acc[5]);
    acc[6] = fmaf(a3.x, w0, acc[6]); acc[7] = fmaf(a3.y, w0, acc[7]);
  }
  if (j < je && q < je - j) {  // tail: r in {1,2,3}, quarter q < r handles edge j+q
    int s0 = ssrc[j + q];
    float w0 = dinv[s0];
    uint4 u = Hb4[(size_t)s0 * 16 + ql];
    float2 a0 = upk(u.x), a1 = upk(u.y), a2 = upk(u.z), a3 = upk(u.w);
    acc[0] = fmaf(a0.x, w0, acc[0]); acc[1] = fmaf(a0.y, w0, acc[1]);
    acc[2] = fmaf(a1.x, w0, acc[2]); acc[3] = fmaf(a1.y, w0, acc[3]);
    acc[4] = fmaf(a2.x, w0, acc[4]); acc[5] = fmaf(a2.y, w0, acc[5]);
    acc[6] = fmaf(a3.x, w0, acc[6]); acc[7] = fmaf(a3.y, w0, acc[7]);
  }
#pragma unroll
  for (int k = 0; k < 8; ++k) {
    acc[k] += __shfl_xor(acc[k], 16);
    acc[k] += __shfl_xor(acc[k], 32);
  }
  if (q == 0) {
    float4 bb0 = ((const float4*)b1)[2 * ql];
    float4 bb1 = ((const float4*)b1)[2 * ql + 1];
    float h0 = fmaxf(fmaf(dn, acc[0], bb0.x), 0.f);
    float h1 = fmaxf(fmaf(dn, acc[1], bb0.y), 0.f);
    float h2 = fmaxf(fmaf(dn, acc[2], bb0.z), 0.f);
    float h3 = fmaxf(fmaf(dn, acc[3], bb0.w), 0.f);
    float h4 = fmaxf(fmaf(dn, acc[4], bb1.x), 0.f);
    float h5 = fmaxf(fmaf(dn, acc[5], bb1.y), 0.f);
    float h6 = fmaxf(fmaf(dn, acc[6], bb1.z), 0.f);
    float h7 = fmaxf(fmaf(dn, acc[7], bb1.w), 0.f);
    ((uint4*)H2)[(size_t)n * 16 + ql] =
        make_uint4(pk2(h0, h1), pk2(h2, h3), pk2(h4, h5), pk2(h6, h7));
  }
}

// ---------------- MFMA GEMM-2: 64 rows x 64 cols per block ----------------
__global__ __launch_bounds__(256) void k_mm2(const unsigned* __restrict__ H2,
                                             const unsigned short* __restrict__ W2T,
                                             const float* __restrict__ dinv,
                                             unsigned* __restrict__ H3u) {
  __shared__ __attribute__((aligned(16))) unsigned smem[8192];
  uint4* w2t4 = (uint4*)smem;
  uint4* xs4  = (uint4*)(smem + 4096);
  const int tid = threadIdx.x;
  const int base = blockIdx.x * 64;
  const uint4* W2Tg = (const uint4*)W2T;
  const uint4* H2v = (const uint4*)H2;
#pragma unroll
  for (int it = 0; it < 4; ++it) w2t4[tid + 256 * it] = W2Tg[tid + 256 * it];
#pragma unroll
  for (int it = 0; it < 4; ++it) {
    int j = tid + 256 * it;
    int row = j >> 4, c16 = j & 15;
    int grow = base + row;
    uint4 v = (grow < NN) ? H2v[(size_t)grow * 16 + c16] : make_uint4(0, 0, 0, 0);
    xs4[row * 16 + (c16 ^ (row & 7))] = v;
  }
  __syncthreads();
  const int lane = tid & 63, wv = tid >> 6;
  const int l7 = lane & 7, lg = lane >> 4;
  f32x4 acc[4];
#pragma unroll
  for (int c = 0; c < 4; ++c) acc[c] = (f32x4){0.f, 0.f, 0.f, 0.f};
  const int arow = wv * 16 + (lane & 15);
#pragma unroll
  for (int kk = 0; kk < 4; ++kk) {
    int kcc = kk * 4 + lg;
    U4 a; a.u = xs4[arow * 16 + (kcc ^ l7)];
#pragma unroll
    for (int c = 0; c < 4; ++c) {
      int n = c * 16 + (lane & 15);
      U4 b; b.u = w2t4[n * 16 + (kcc ^ l7)];
      acc[c] = __builtin_amdgcn_mfma_f32_16x16x32_bf16(a.h, b.h, acc[c], 0, 0, 0);
    }
  }
#pragma unroll
  for (int c = 0; c < 4; ++c) {
#pragma unroll
    for (int r = 0; r < 4; ++r) {
      int grow = base + wv * 16 + lg * 4 + r;
      float dn = (grow < NN) ? dinv[grow] : 0.f;
      unsigned mb = f2bf(acc[c][r] * dn);
      unsigned ob = (unsigned)__shfl_xor((int)mb, 1);
      if (((lane & 1) == 0) && grow < NN)
        H3u[(size_t)grow * 32 + c * 8 + ((lane & 15) >> 1)] = mb | (ob << 16);
    }
  }
}

// ---------------- agg2: quarter-wave (16 lanes/edge, uint2 8B loads) ----------------
__global__ __launch_bounds__(256) void k_agg2(const unsigned* __restrict__ H3u,
                                              const int* __restrict__ off,
                                              const unsigned short* __restrict__ ssrc,
                                              const float* __restrict__ dinv,
                                              const float* __restrict__ b2,
                                              float* __restrict__ out) {
  int n = (blockIdx.x * 256 + threadIdx.x) >> 6;
  int lane = threadIdx.x & 63;
  if (n >= NN) return;
  const int q = lane >> 4, ql = lane & 15;
  const uint2* H32 = (const uint2*)H3u;
  float dn = dinv[n];
  int jb = off[n], je = off[n + 1];
  float acc[4] = {0.f, 0.f, 0.f, 0.f};
  if (q == 0) {  // self term (H3 prescaled)
    uint2 u = H32[(size_t)n * 16 + ql];
    float2 a0 = upk(u.x), a1 = upk(u.y);
    acc[0] = a0.x; acc[1] = a0.y; acc[2] = a1.x; acc[3] = a1.y;
  }
  int j = jb;
  for (; j + 15 < je; j += 16) {  // 4 edges per quarter
    int s[4]; uint2 u[4];
#pragma unroll
    for (int k = 0; k < 4; ++k) s[k] = ssrc[j + 4 * k + q];
#pragma unroll
    for (int k = 0; k < 4; ++k) u[k] = H32[(size_t)s[k] * 16 + ql];
#pragma unroll
    for (int k = 0; k < 4; ++k) {
      float2 a0 = upk(u[k].x), a1 = upk(u[k].y);
      acc[0] += a0.x; acc[1] += a0.y; acc[2] += a1.x; acc[3] += a1.y;
    }
  }
  for (; j + 7 < je; j += 8) {  // 2 edges per quarter
    int s[2]; uint2 u[2];
#pragma unroll
    for (int k = 0; k < 2; ++k) s[k] = ssrc[j + 4 * k + q];
#pragma unroll
    for (int k = 0; k < 2; ++k) u[k] = H32[(size_t)s[k] * 16 + ql];
#pragma unroll
    for (int k = 0; k < 2; ++k) {
      float2 a0 = upk(u[k].x), a1 = upk(u[k].y);
      acc[0] += a0.x; acc[1] += a0.y; acc[2] += a1.x; acc[3] += a1.y;
    }
  }
  for (; j + 3 < je; j += 4) {  // 1 edge per quarter
    uint2 u = H32[(size_t)ssrc[j + q] * 16 + ql];
    float2 a0 = upk(u.x), a1 = upk(u.y);
    acc[0] += a0.x; acc[1] += a0.y; acc[2] += a1.x; acc[3] += a1.y;
  }
  if (j < je && q < je - j) {  // tail
    uint2 u = H32[(size_t)ssrc[j + q] * 16 + ql];
    float2 a0 = upk(u.x), a1 = upk(u.y);
    acc[0] += a0.x; acc[1] += a0.y; acc[2] += a1.x; acc[3] += a1.y;
  }
#pragma unroll
  for (int k = 0; k < 4; ++k) {
    acc[k] += __shfl_xor(acc[k], 16);
    acc[k] += __shfl_xor(acc[k], 32);
  }
  if (q == 0) {
    float4 bb = ((const float4*)b2)[ql];
    ((float4*)out)[(size_t)n * 16 + ql] =
        make_float4(fmaxf(fmaf(dn, acc[0], bb.x), 0.f),
                    fmaxf(fmaf(dn, acc[1], bb.y), 0.f),
                    fmaxf(fmaf(dn, acc[2], bb.z), 0.f),
                    fmaxf(fmaf(dn, acc[3], bb.w), 0.f));
  }
}

extern "C" void kernel_launch(void* const* d_in, const int* in_sizes, int n_in,
                              void* d_out, int out_size, void* d_ws, size_t ws_size,
                              hipStream_t stream) {
  const float* x  = (const float*)d_in[0];
  const int*   ei = (const int*)d_in[1];
  const float* W1 = (const float*)d_in[2];
  const float* b1 = (const float*)d_in[3];
  const float* W2 = (const float*)d_in[4];
  const float* b2 = (const float*)d_in[5];
  const int* esrc = ei;
  const int* edst = ei + NE;

  char* ws = (char*)d_ws;
  unsigned* gcur  = (unsigned*)(ws + 0);
  int*      off   = (int*)(ws + 2048);
  float*    dinv  = (float*)(ws + 204800);
  unsigned short* ssrc = (unsigned short*)(ws + 405504);   // 1.6 MB
  unsigned short* W1T  = (unsigned short*)(ws + 2013184);  // 32 KB
  unsigned short* W2T  = (unsigned short*)(ws + 2045952);  // 16 KB
  unsigned* part  = (unsigned*)(ws + 2097152);             // ~4 MB
  unsigned* Hb    = (unsigned*)(ws + 6291456);             // 12.8 MB
  unsigned* H2    = (unsigned*)(ws + 19922944);            // 12.8 MB
  unsigned* H3    = (unsigned*)(ws + 33554432);            // 6.4 MB

  hipLaunchKernelGGL(k_prep, dim3(64), dim3(256), 0, stream, W1, W2, W1T, W2T, gcur);
  hipLaunchKernelGGL(k_partmm1, dim3(NPART + (NN + 63) / 64), dim3(256), 0, stream,
                     esrc, edst, gcur, part, x, W1T, Hb);
  hipLaunchKernelGGL(k_bucket, dim3(NBUCK), dim3(256), 0, stream,
                     gcur, part, off, dinv, ssrc);
  hipLaunchKernelGGL(k_agg1, dim3((NN + 3) / 4), dim3(256), 0, stream,
                     Hb, off, ssrc, dinv, b1, H2);
  hipLaunchKernelGGL(k_mm2, dim3((NN + 63) / 64), dim3(256), 0, stream,
                     H2, W2T, dinv, H3);
  hipLaunchKernelGGL(k_agg2, dim3((NN + 3) / 4), dim3(256), 0, stream,
                     H3, off, ssrc, dinv, b2, (float*)d_out);
}